// Round 1
// baseline (4111.027 us; speedup 1.0000x reference)
//
#include <hip/hip_runtime.h>
#include <stdint.h>

// Problem constants (B=4, C=256, H=W=64, PATCH=3, STRIDE=1)
#define NP   3844   // npatches = 62*62; also per-batch feat pixels (62*62)
#define ND   62     // n2 = n3
#define NC   256
#define HW   64
#define KTOT 2304   // C*3*3
#define BK   16
#define TM   64
#define TN   128

__device__ __forceinline__ unsigned int orderf(float v) {
    unsigned int u = __float_as_uint(v);
    return (u & 0x80000000u) ? ~u : (u | 0x80000000u);
}

__global__ __launch_bounds__(256) void init_keys(unsigned long long* keys) {
    int i = blockIdx.x * 256 + threadIdx.x;
    if (i < 4 * NP) keys[i] = 0ull;
}

// Fused fp32 GEMM (content-windows x style-patches) + enc_bias + argmax.
// Block tile: TM=64 content pixels x TN=128 patches, K-chunks of BK=16.
__global__ __launch_bounds__(256) void feat_argmax(
    const float* __restrict__ content,
    const float* __restrict__ style,
    const float* __restrict__ enc_bias,
    unsigned long long* __restrict__ keys)
{
    __shared__ float As[BK][TM];               // 4 KB
    __shared__ float Bs[BK][TN];               // 8 KB
    __shared__ unsigned long long red[TM][16]; // 8 KB

    const int tid = threadIdx.x;
    const int tx = tid & 15;   // n-direction: 16 threads x 8 cols = 128
    const int ty = tid >> 4;   // m-direction: 16 threads x 4 rows = 64
    const int b  = blockIdx.z;
    const int q0 = blockIdx.y * TM;   // content-pixel tile base (per batch)
    const int p0 = blockIdx.x * TN;   // patch tile base
    const float* __restrict__ cb = content + (size_t)b * NC * HW * HW;

    // A loader: each thread owns one m (content pixel), loads 4 k's per chunk
    const int mA = tid & 63;
    const int qA = q0 + mA;
    const bool vA = (qA < NP);
    int offA = 0;
    if (vA) { int y = qA / ND; int x = qA - y * ND; offA = y * HW + x; }
    const int kkA0 = tid >> 6;   // 0..3

    // B loader: each thread owns one n (patch), loads 8 k's per chunk
    const int nB = tid & 127;
    const int pB = p0 + nB;
    const bool vB = (pB < NP);
    int offB = 0;
    if (vB) { int pi = pB / ND; int pj = pB - pi * ND; offB = pi * HW + pj; }
    const int kkB0 = tid >> 7;   // 0..1

    float acc[4][8];
    #pragma unroll
    for (int i = 0; i < 4; ++i)
        #pragma unroll
        for (int j = 0; j < 8; ++j) acc[i][j] = 0.f;

    for (int k0 = 0; k0 < KTOT; k0 += BK) {
        #pragma unroll
        for (int j = 0; j < 4; ++j) {
            int kk = kkA0 + j * 4;
            int k = k0 + kk;
            int c = k / 9; int r = k - c * 9; int u = r / 3; int v = r - u * 3;
            float val = 0.f;
            if (vA) val = cb[c * (HW * HW) + offA + u * HW + v];
            As[kk][mA] = val;
        }
        #pragma unroll
        for (int j = 0; j < 8; ++j) {
            int kk = kkB0 + j * 2;
            int k = k0 + kk;
            int c = k / 9; int r = k - c * 9; int u = r / 3; int v = r - u * 3;
            float val = 0.f;
            if (vB) val = style[c * (HW * HW) + offB + u * HW + v];
            Bs[kk][nB] = val;
        }
        __syncthreads();
        #pragma unroll
        for (int kk = 0; kk < BK; ++kk) {
            float a[4], bb[8];
            #pragma unroll
            for (int i = 0; i < 4; ++i) a[i] = As[kk][ty * 4 + i];
            #pragma unroll
            for (int j = 0; j < 8; ++j) bb[j] = Bs[kk][tx * 8 + j];
            #pragma unroll
            for (int i = 0; i < 4; ++i)
                #pragma unroll
                for (int j = 0; j < 8; ++j)
                    acc[i][j] = fmaf(a[i], bb[j], acc[i][j]);
        }
        __syncthreads();
    }

    // Epilogue: + enc_bias[p], argmax over this block's 128 patches.
    float eb[8];
    #pragma unroll
    for (int j = 0; j < 8; ++j) {
        int p = p0 + tx * 8 + j;
        eb[j] = (p < NP) ? enc_bias[p] : 0.f;
    }
    #pragma unroll
    for (int i = 0; i < 4; ++i) {
        unsigned long long best = 0ull;
        #pragma unroll
        for (int j = 0; j < 8; ++j) {
            int p = p0 + tx * 8 + j;
            if (p < NP) {
                float v = acc[i][j] + eb[j];
                // pack: high = order-preserving f32, low = NP-1-p so that on
                // exact value ties max() picks the SMALLEST p (jnp.argmax rule)
                unsigned long long key = ((unsigned long long)orderf(v) << 32)
                                       | (unsigned int)(NP - 1 - p);
                best = best > key ? best : key;
            }
        }
        red[ty * 4 + i][tx] = best;
    }
    __syncthreads();
    if (tid < TM) {
        unsigned long long best = 0ull;
        #pragma unroll
        for (int t = 0; t < 16; ++t) {
            unsigned long long k = red[tid][t];
            best = best > k ? best : k;
        }
        int q = q0 + tid;
        if (q < NP) atomicMax(&keys[(size_t)b * NP + q], best);
    }
}

// out[b,c,h,w] = (dec_bias[c] + sum_{valid u,v} style[c, pi+u, pj+v]) /
//                (cnt_valid + intra_bias[c]),  p = idx[b, h-u, w-v]
__global__ __launch_bounds__(256) void produce_out(
    const float* __restrict__ style,
    const float* __restrict__ dec_bias,
    const float* __restrict__ intra_bias,
    const unsigned long long* __restrict__ keys,
    float* __restrict__ out)
{
    const int bh = blockIdx.x;
    const int b = bh >> 6;
    const int h = bh & 63;
    const int cg = blockIdx.y;       // 64 groups of 4 channels
    const int tid = threadIdx.x;
    const int w = tid & 63;
    const int c = cg * 4 + (tid >> 6);

    __shared__ int pidx[3][ND];
    if (tid < 3 * ND) {
        int rr = tid / ND, jj = tid - rr * ND;
        int hh = h - 2 + rr;
        int p = 0;
        if (hh >= 0 && hh < ND) {
            unsigned long long key = keys[(size_t)b * NP + hh * ND + jj];
            p = NP - 1 - (int)(key & 0xFFFFFFFFull);
        }
        pidx[rr][jj] = p;
    }
    __syncthreads();

    float s = 0.f;
    int cnt = 0;
    #pragma unroll
    for (int u = 0; u < 3; ++u) {
        int hh = h - u;
        if (hh < 0 || hh >= ND) continue;
        #pragma unroll
        for (int v = 0; v < 3; ++v) {
            int ww = w - v;
            if (ww < 0 || ww >= ND) continue;
            int p = pidx[2 - u][ww];
            int pi = p / ND, pj = p - pi * ND;
            s += style[(c * HW + pi + u) * HW + pj + v];
            cnt++;
        }
    }
    out[(((size_t)b * NC + c) * HW + h) * HW + w] =
        (s + dec_bias[c]) / ((float)cnt + intra_bias[c]);
}

extern "C" void kernel_launch(void* const* d_in, const int* in_sizes, int n_in,
                              void* d_out, int out_size, void* d_ws, size_t ws_size,
                              hipStream_t stream) {
    const float* content    = (const float*)d_in[0];
    const float* style      = (const float*)d_in[1];
    const float* enc_bias   = (const float*)d_in[2];
    const float* dec_bias   = (const float*)d_in[3];
    const float* intra_bias = (const float*)d_in[4];
    float* out = (float*)d_out;
    unsigned long long* keys = (unsigned long long*)d_ws;  // 4*3844*8 = 123 KB

    init_keys<<<(4 * NP + 255) / 256, 256, 0, stream>>>(keys);

    dim3 grid1((NP + TN - 1) / TN, (NP + TM - 1) / TM, 4);  // 31 x 61 x 4
    feat_argmax<<<grid1, 256, 0, stream>>>(content, style, enc_bias, keys);

    dim3 grid2(4 * 64, NC / 4);  // (b,h) x channel-groups
    produce_out<<<grid2, 256, 0, stream>>>(style, dec_bias, intra_bias, keys, out);
}

// Round 2
// 934.280 us; speedup vs baseline: 4.4002x; 4.4002x over previous
//
#include <hip/hip_runtime.h>
#include <stdint.h>

// Problem constants (B=4, C=256, H=W=64, PATCH=3, STRIDE=1)
#define NP   3844   // 62*62 patches == per-batch feat pixels
#define ND   62
#define NC   256
#define HW   64
#define SP   4096   // 64*64 pixels per image
#define KTOT 2304

typedef __attribute__((ext_vector_type(8))) short short8;
typedef __attribute__((ext_vector_type(4))) float float4v;
typedef unsigned long long u64;

__device__ __forceinline__ unsigned int orderf(float v) {
    unsigned int u = __float_as_uint(v);
    return (u & 0x80000000u) ? ~u : (u | 0x80000000u);
}
__device__ __forceinline__ float bf2f(unsigned short h) {
    return __uint_as_float(((unsigned int)h) << 16);
}

// ---------------------------------------------------------------------------
// Kernel 1: G[s][t] = sum_c content_b[c][s] * style[c][t], bf16x3-split MFMA,
// output stored as bf16 (RNE). Tile 128x128, BK=32, K=256.
// ---------------------------------------------------------------------------
#define ROWH 40   // LDS row stride in halves (32 k + 8 pad) = 80 B, 16-aligned

__global__ __launch_bounds__(256, 2) void g_gemm(
    const float* __restrict__ contentb,   // [256][4096] for this batch
    const float* __restrict__ style,      // [256][4096]
    unsigned short* __restrict__ Gb)      // [4096][4096] bf16
{
    __shared__ __attribute__((aligned(16))) short Ah[128 * ROWH];
    __shared__ __attribute__((aligned(16))) short Al[128 * ROWH];
    __shared__ __attribute__((aligned(16))) short Bh[128 * ROWH];
    __shared__ __attribute__((aligned(16))) short Bl[128 * ROWH];

    const int tid  = threadIdx.x;
    const int s0   = blockIdx.x * 128;
    const int t0   = blockIdx.y * 128;
    const int wave = tid >> 6, lane = tid & 63;
    const int wm = (wave >> 1) * 64, wn = (wave & 1) * 64;
    const int fr = lane & 15;   // frag row/col
    const int fq = lane >> 4;   // quad -> k-offset fq*8

    const int sm = tid & 127;   // staging: row owner
    const int sl = tid >> 7;    // staging: k-half (0/1)

    float4v acc[4][4];
    #pragma unroll
    for (int i = 0; i < 4; ++i)
        #pragma unroll
        for (int j = 0; j < 4; ++j) acc[i][j] = (float4v)(0.f);

    for (int k0 = 0; k0 < 256; k0 += 32) {
        __syncthreads();
        #pragma unroll
        for (int h = 0; h < 2; ++h) {
            const float* src = h ? style : contentb;
            const int rb = h ? t0 : s0;
            short* dh = h ? Bh : Ah;
            short* dl = h ? Bl : Al;
            float v[16];
            #pragma unroll
            for (int j = 0; j < 16; ++j)
                v[j] = src[(size_t)(k0 + sl * 16 + j) * SP + rb + sm];
            short8 h0, h1, l0, l1;
            #pragma unroll
            for (int j = 0; j < 8; ++j) {
                unsigned ua = __float_as_uint(v[j]);
                unsigned ub = __float_as_uint(v[j + 8]);
                h0[j] = (short)(ua >> 16);
                h1[j] = (short)(ub >> 16);
                float ra = v[j]     - __uint_as_float(ua & 0xffff0000u);
                float rb2 = v[j + 8] - __uint_as_float(ub & 0xffff0000u);
                l0[j] = (short)(__float_as_uint(ra) >> 16);
                l1[j] = (short)(__float_as_uint(rb2) >> 16);
            }
            *(short8*)(dh + sm * ROWH + sl * 16)     = h0;
            *(short8*)(dh + sm * ROWH + sl * 16 + 8) = h1;
            *(short8*)(dl + sm * ROWH + sl * 16)     = l0;
            *(short8*)(dl + sm * ROWH + sl * 16 + 8) = l1;
        }
        __syncthreads();

        short8 ah[4], al[4], bh[4], bl[4];
        #pragma unroll
        for (int f = 0; f < 4; ++f) {
            const int ra = (wm + f * 16 + fr) * ROWH + fq * 8;
            const int rb = (wn + f * 16 + fr) * ROWH + fq * 8;
            ah[f] = *(const short8*)(Ah + ra);
            al[f] = *(const short8*)(Al + ra);
            bh[f] = *(const short8*)(Bh + rb);
            bl[f] = *(const short8*)(Bl + rb);
        }
        #pragma unroll
        for (int fm = 0; fm < 4; ++fm)
            #pragma unroll
            for (int fn = 0; fn < 4; ++fn) {
                acc[fm][fn] = __builtin_amdgcn_mfma_f32_16x16x32_bf16(ah[fm], bh[fn], acc[fm][fn], 0, 0, 0);
                acc[fm][fn] = __builtin_amdgcn_mfma_f32_16x16x32_bf16(ah[fm], bl[fn], acc[fm][fn], 0, 0, 0);
                acc[fm][fn] = __builtin_amdgcn_mfma_f32_16x16x32_bf16(al[fm], bh[fn], acc[fm][fn], 0, 0, 0);
            }
    }

    // store: C/D layout col=lane&15, row=(lane>>4)*4+reg
    #pragma unroll
    for (int fm = 0; fm < 4; ++fm)
        #pragma unroll
        for (int fn = 0; fn < 4; ++fn)
            #pragma unroll
            for (int r = 0; r < 4; ++r) {
                unsigned u = __float_as_uint(acc[fm][fn][r]);
                unsigned short o = (unsigned short)((u + 0x7fffu + ((u >> 16) & 1u)) >> 16);
                Gb[(size_t)(s0 + wm + fm * 16 + fq * 4 + r) * SP + t0 + wn + fn * 16 + fr] = o;
            }
}

// ---------------------------------------------------------------------------
// Kernel 2: stencil feat[q][p] = sum_9 G[s+d][t+d] + enc_bias[p]; per-(q,ptile)
// top-2 packed keys -> cand. q-tile 8x8, p-tile 4(pi)x32(pj) -> 32 p-tiles.
// ---------------------------------------------------------------------------
#define STP 209   // LDS t-rect stride in halves (6*34=204 +5)

__global__ __launch_bounds__(256) void stencil_cand(
    const unsigned short* __restrict__ Gb,
    const float* __restrict__ enc_bias,
    u64* __restrict__ cand, int b)
{
    __shared__ unsigned short Gt[100 * STP];   // ~41.8 KB
    __shared__ u64 Mrg[64 * 4 * 2];            // 4 KB

    const int qT = blockIdx.x;                 // 0..63
    const int pT = blockIdx.y;                 // 0..31
    const int y0 = (qT >> 3) * 8, x0 = (qT & 7) * 8;
    const int ti0 = (pT >> 1) * 4, tj0 = (pT & 1) * 32;
    const int tid = threadIdx.x;

    for (int e = tid; e < 100 * 204; e += 256) {
        int s_l = e / 204; int te = e - s_l * 204;
        int ri = te / 34;  int cj = te - ri * 34;
        int sy = y0 + s_l / 10;
        int sx = x0 + (s_l - (s_l / 10) * 10);
        int ty = ti0 + ri, tx = tj0 + cj;
        if (sy < 64 && sx < 64 && ty < 64 && tx < 64)
            Gt[s_l * STP + te] = Gb[(size_t)(sy * 64 + sx) * SP + ty * 64 + tx];
    }
    __syncthreads();

    const int q_l = tid & 63, pq = tid >> 6;
    const int qy = q_l >> 3, qx = q_l & 7;
    const int y = y0 + qy, x = x0 + qx;
    const bool vq = (y < ND) && (x < ND);
    const int pi = ti0 + pq;
    const int base0 = (qy * 10 + qx) * STP + pq * 34;

    // offsets: d2 = (u*10+v)*STP + u*34 + v
    int OFF[9];
    #pragma unroll
    for (int u = 0; u < 3; ++u)
        #pragma unroll
        for (int v = 0; v < 3; ++v)
            OFF[u * 3 + v] = (u * 10 + v) * STP + u * 34 + v;

    u64 k1 = 0, k2 = 0;
    if (vq && pi < ND) {
        for (int pjl = 0; pjl < 32; ++pjl) {
            int pj = tj0 + pjl;
            if (pj >= ND) break;
            int base = base0 + pjl;
            float f = 0.f;
            #pragma unroll
            for (int d = 0; d < 9; ++d) f += bf2f(Gt[base + OFF[d]]);
            int p = pi * ND + pj;
            f += enc_bias[p];
            u64 key = ((u64)orderf(f) << 32) | (unsigned int)(NP - 1 - p);
            if (key > k1) { k2 = k1; k1 = key; }
            else if (key > k2) { k2 = key; }
        }
    }
    Mrg[(q_l * 4 + pq) * 2]     = k1;
    Mrg[(q_l * 4 + pq) * 2 + 1] = k2;
    __syncthreads();
    if (pq == 0 && vq) {
        u64 b1 = 0, b2 = 0;
        #pragma unroll
        for (int t = 0; t < 8; ++t) {
            u64 k = Mrg[q_l * 8 + t];
            if (k > b1) { b2 = b1; b1 = k; }
            else if (k > b2) { b2 = k; }
        }
        int q = y * ND + x;
        size_t o = ((size_t)(b * NP + q) * 32 + pT) * 2;
        cand[o] = b1; cand[o + 1] = b2;
    }
}

// ---------------------------------------------------------------------------
// Kernel 3: exact fp32 rescore of global top-2 candidates per q -> idx
// thread = (q, cand); pairs exchange via LDS.
// ---------------------------------------------------------------------------
__global__ __launch_bounds__(256) void rescore(
    const float* __restrict__ content,
    const float* __restrict__ style,
    const float* __restrict__ enc_bias,
    const u64* __restrict__ cand,
    int* __restrict__ idx)
{
    __shared__ float sc[256];
    __shared__ int   pp[256];
    const int gid = blockIdx.x * 256 + threadIdx.x;
    const int qa = gid >> 1, cd = gid & 1;
    const bool valid = qa < 4 * NP;
    float score = -1e30f; int p = 0;
    if (valid) {
        int b = qa / NP, q = qa - b * NP;
        int y = q / ND, x = q - y * ND;
        const u64* cp = cand + (size_t)qa * 64;
        u64 k1 = 0, k2 = 0;
        for (int i = 0; i < 64; ++i) {
            u64 k = cp[i];
            if (k > k1) { k2 = k1; k1 = k; }
            else if (k > k2) { k2 = k; }
        }
        u64 kk = cd ? k2 : k1;
        p = NP - 1 - (int)(kk & 0xffffffffu);
        int pi = p / ND, pj = p - pi * ND;
        const float* cb = content + (size_t)b * NC * SP + y * 64 + x;
        const float* sb = style + pi * 64 + pj;
        float s = 0.f;
        for (int c = 0; c < NC; ++c) {
            const float* cw = cb + (size_t)c * SP;
            const float* sw = sb + (size_t)c * SP;
            #pragma unroll
            for (int u = 0; u < 3; ++u)
                #pragma unroll
                for (int v = 0; v < 3; ++v)
                    s = fmaf(cw[u * 64 + v], sw[u * 64 + v], s);
        }
        score = s + enc_bias[p];
    }
    sc[threadIdx.x] = score; pp[threadIdx.x] = p;
    __syncthreads();
    if (valid && cd == 0) {
        float s0 = sc[threadIdx.x], s1 = sc[threadIdx.x + 1];
        int p0 = pp[threadIdx.x], p1 = pp[threadIdx.x + 1];
        int win = (s1 > s0 || (s1 == s0 && p1 < p0)) ? p1 : p0;
        idx[qa] = win;
    }
}

// ---------------------------------------------------------------------------
// Kernel 4: output (validated in round 1, now reads int idx)
// ---------------------------------------------------------------------------
__global__ __launch_bounds__(256) void produce_out(
    const float* __restrict__ style,
    const float* __restrict__ dec_bias,
    const float* __restrict__ intra_bias,
    const int* __restrict__ idx,
    float* __restrict__ out)
{
    const int bh = blockIdx.x;
    const int b = bh >> 6;
    const int h = bh & 63;
    const int cg = blockIdx.y;
    const int tid = threadIdx.x;
    const int w = tid & 63;
    const int c = cg * 4 + (tid >> 6);

    __shared__ int pidx[3][ND];
    if (tid < 3 * ND) {
        int rr = tid / ND, jj = tid - rr * ND;
        int hh = h - 2 + rr;
        int p = 0;
        if (hh >= 0 && hh < ND) p = idx[b * NP + hh * ND + jj];
        pidx[rr][jj] = p;
    }
    __syncthreads();

    float s = 0.f;
    int cnt = 0;
    #pragma unroll
    for (int u = 0; u < 3; ++u) {
        int hh = h - u;
        if (hh < 0 || hh >= ND) continue;
        #pragma unroll
        for (int v = 0; v < 3; ++v) {
            int ww = w - v;
            if (ww < 0 || ww >= ND) continue;
            int p = pidx[2 - u][ww];
            int pi = p / ND, pj = p - pi * ND;
            s += style[(c * HW + pi + u) * HW + pj + v];
            cnt++;
        }
    }
    out[(((size_t)b * NC + c) * HW + h) * HW + w] =
        (s + dec_bias[c]) / ((float)cnt + intra_bias[c]);
}

// ---------------------------------------------------------------------------
// Fallback path (round-1, known-good): fp32 VALU GEMM + argmax keys
// ---------------------------------------------------------------------------
#define FBK 16
#define FTM 64
#define FTN 128

__global__ __launch_bounds__(256) void init_keys(u64* keys) {
    int i = blockIdx.x * 256 + threadIdx.x;
    if (i < 4 * NP) keys[i] = 0ull;
}

__global__ __launch_bounds__(256) void feat_argmax(
    const float* __restrict__ content,
    const float* __restrict__ style,
    const float* __restrict__ enc_bias,
    u64* __restrict__ keys)
{
    __shared__ float As[FBK][FTM];
    __shared__ float Bs[FBK][FTN];
    __shared__ u64 red[FTM][16];

    const int tid = threadIdx.x;
    const int tx = tid & 15;
    const int ty = tid >> 4;
    const int b  = blockIdx.z;
    const int q0 = blockIdx.y * FTM;
    const int p0 = blockIdx.x * FTN;
    const float* __restrict__ cb = content + (size_t)b * NC * SP;

    const int mA = tid & 63;
    const int qA = q0 + mA;
    const bool vA = (qA < NP);
    int offA = 0;
    if (vA) { int y = qA / ND; int x = qA - y * ND; offA = y * HW + x; }
    const int kkA0 = tid >> 6;

    const int nB = tid & 127;
    const int pB = p0 + nB;
    const bool vB = (pB < NP);
    int offB = 0;
    if (vB) { int pi = pB / ND; int pj = pB - pi * ND; offB = pi * HW + pj; }
    const int kkB0 = tid >> 7;

    float acc[4][8];
    #pragma unroll
    for (int i = 0; i < 4; ++i)
        #pragma unroll
        for (int j = 0; j < 8; ++j) acc[i][j] = 0.f;

    for (int k0 = 0; k0 < KTOT; k0 += FBK) {
        #pragma unroll
        for (int j = 0; j < 4; ++j) {
            int kk = kkA0 + j * 4;
            int k = k0 + kk;
            int c = k / 9; int r = k - c * 9; int u = r / 3; int v = r - u * 3;
            float val = 0.f;
            if (vA) val = cb[c * SP + offA + u * HW + v];
            As[kk][mA] = val;
        }
        #pragma unroll
        for (int j = 0; j < 8; ++j) {
            int kk = kkB0 + j * 2;
            int k = k0 + kk;
            int c = k / 9; int r = k - c * 9; int u = r / 3; int v = r - u * 3;
            float val = 0.f;
            if (vB) val = style[c * SP + offB + u * HW + v];
            Bs[kk][nB] = val;
        }
        __syncthreads();
        #pragma unroll
        for (int kk = 0; kk < FBK; ++kk) {
            float a[4], bb[8];
            #pragma unroll
            for (int i = 0; i < 4; ++i) a[i] = As[kk][ty * 4 + i];
            #pragma unroll
            for (int j = 0; j < 8; ++j) bb[j] = Bs[kk][tx * 8 + j];
            #pragma unroll
            for (int i = 0; i < 4; ++i)
                #pragma unroll
                for (int j = 0; j < 8; ++j)
                    acc[i][j] = fmaf(a[i], bb[j], acc[i][j]);
        }
        __syncthreads();
    }

    float eb[8];
    #pragma unroll
    for (int j = 0; j < 8; ++j) {
        int p = p0 + tx * 8 + j;
        eb[j] = (p < NP) ? enc_bias[p] : 0.f;
    }
    #pragma unroll
    for (int i = 0; i < 4; ++i) {
        u64 best = 0ull;
        #pragma unroll
        for (int j = 0; j < 8; ++j) {
            int p = p0 + tx * 8 + j;
            if (p < NP) {
                float v = acc[i][j] + eb[j];
                u64 key = ((u64)orderf(v) << 32) | (unsigned int)(NP - 1 - p);
                best = best > key ? best : key;
            }
        }
        red[ty * 4 + i][tx] = best;
    }
    __syncthreads();
    if (tid < FTM) {
        u64 best = 0ull;
        #pragma unroll
        for (int t = 0; t < 16; ++t) {
            u64 k = red[tid][t];
            best = best > k ? best : k;
        }
        int q = q0 + tid;
        if (q < NP) atomicMax(&keys[(size_t)b * NP + q], best);
    }
}

__global__ __launch_bounds__(256) void key2idx(const u64* keys, int* idx) {
    int i = blockIdx.x * 256 + threadIdx.x;
    if (i < 4 * NP) idx[i] = NP - 1 - (int)(keys[i] & 0xffffffffu);
}

// ---------------------------------------------------------------------------
extern "C" void kernel_launch(void* const* d_in, const int* in_sizes, int n_in,
                              void* d_out, int out_size, void* d_ws, size_t ws_size,
                              hipStream_t stream) {
    const float* content    = (const float*)d_in[0];
    const float* style      = (const float*)d_in[1];
    const float* enc_bias   = (const float*)d_in[2];
    const float* dec_bias   = (const float*)d_in[3];
    const float* intra_bias = (const float*)d_in[4];
    float* out = (float*)d_out;

    const size_t G_BYTES    = (size_t)SP * SP * 2;            // 33,554,432
    const size_t CAND_BYTES = (size_t)4 * NP * 32 * 2 * 8;    //  1,968,128
    const size_t IDX_BYTES  = (size_t)4 * NP * 4;             //     61,504
    const size_t NEED = G_BYTES + CAND_BYTES + IDX_BYTES;

    if (ws_size >= NEED) {
        unsigned short* Gb = (unsigned short*)d_ws;
        u64* cand = (u64*)((char*)d_ws + G_BYTES);
        int* idx  = (int*)((char*)d_ws + G_BYTES + CAND_BYTES);

        for (int b = 0; b < 4; ++b) {
            g_gemm<<<dim3(32, 32), 256, 0, stream>>>(
                content + (size_t)b * NC * SP, style, Gb);
            stencil_cand<<<dim3(64, 32), 256, 0, stream>>>(
                Gb, enc_bias, cand, b);
        }
        rescore<<<dim3(121), 256, 0, stream>>>(content, style, enc_bias, cand, idx);
        produce_out<<<dim3(4 * 64, NC / 4), 256, 0, stream>>>(
            style, dec_bias, intra_bias, idx, out);
    } else {
        u64* keys = (u64*)d_ws;
        int* idx  = (int*)((char*)d_ws + (size_t)4 * NP * 8);
        init_keys<<<(4 * NP + 255) / 256, 256, 0, stream>>>(keys);
        feat_argmax<<<dim3((NP + FTN - 1) / FTN, (NP + FTM - 1) / FTM, 4), 256, 0, stream>>>(
            content, style, enc_bias, keys);
        key2idx<<<(4 * NP + 255) / 256, 256, 0, stream>>>(keys, idx);
        produce_out<<<dim3(4 * 64, NC / 4), 256, 0, stream>>>(
            style, dec_bias, intra_bias, idx, out);
    }
}

// Round 3
// 677.522 us; speedup vs baseline: 6.0677x; 1.3790x over previous
//
#include <hip/hip_runtime.h>
#include <stdint.h>

// Problem constants (B=4, C=256, H=W=64, PATCH=3, STRIDE=1)
#define NP   3844   // 62*62 patches == per-batch feat pixels
#define ND   62
#define NC   256
#define HW   64
#define SP   4096   // 64*64 pixels per image
#define KTOT 2304
#define GAP_T 6.0f  // > 2x worst-case bf16 screening error (9*0.25=2.25)

typedef __attribute__((ext_vector_type(8))) short short8;
typedef __attribute__((ext_vector_type(4))) float float4v;
typedef unsigned long long u64;

__device__ __forceinline__ unsigned int orderf(float v) {
    unsigned int u = __float_as_uint(v);
    return (u & 0x80000000u) ? ~u : (u | 0x80000000u);
}
__device__ __forceinline__ float unorderf(unsigned int k) {
    return __uint_as_float((k & 0x80000000u) ? (k ^ 0x80000000u) : ~k);
}
__device__ __forceinline__ float bf2f(unsigned short h) {
    return __uint_as_float(((unsigned int)h) << 16);
}

// ---------------------------------------------------------------------------
// Kernel 0: style_t[s][c] = style[c][s]  (4 MB fp32, for coalesced c-reads)
// ---------------------------------------------------------------------------
__global__ __launch_bounds__(256) void transpose_style(
    const float* __restrict__ style, float* __restrict__ style_t)
{
    __shared__ float t[32][33];
    const int s0 = blockIdx.x * 32;
    const int c0 = blockIdx.y * 32;
    const int col = threadIdx.x & 31, r8 = threadIdx.x >> 5;
    #pragma unroll
    for (int i = 0; i < 4; ++i) {
        int r = r8 + i * 8;
        t[r][col] = style[(size_t)(c0 + r) * SP + s0 + col];
    }
    __syncthreads();
    #pragma unroll
    for (int i = 0; i < 4; ++i) {
        int r = r8 + i * 8;
        style_t[(size_t)(s0 + r) * 256 + c0 + col] = t[col][r];
    }
}

// ---------------------------------------------------------------------------
// Kernel 1: G[s][t] = sum_c content_b[c][s] * style[c][t], bf16x3-split MFMA.
// LDS layout: [k-chunk(4)][row(128)] of short8 -> 16B lane stride, 2-way free.
// ---------------------------------------------------------------------------
__global__ __launch_bounds__(256, 2) void g_gemm(
    const float* __restrict__ contentb,   // [256][4096] for this batch
    const float* __restrict__ style,      // [256][4096]
    unsigned short* __restrict__ Gb)      // [4096][4096] bf16
{
    __shared__ __attribute__((aligned(16))) short Ah[4 * 128 * 8];
    __shared__ __attribute__((aligned(16))) short Al[4 * 128 * 8];
    __shared__ __attribute__((aligned(16))) short Bh[4 * 128 * 8];
    __shared__ __attribute__((aligned(16))) short Bl[4 * 128 * 8];

    const int tid  = threadIdx.x;
    const int s0   = blockIdx.x * 128;
    const int t0   = blockIdx.y * 128;
    const int wave = tid >> 6, lane = tid & 63;
    const int wm = (wave >> 1) * 64, wn = (wave & 1) * 64;
    const int fr = lane & 15;   // frag row/col
    const int fq = lane >> 4;   // quad -> k-chunk

    const int sm = tid & 127;   // staging: row owner
    const int sl = tid >> 7;    // staging: k-half (0/1)

    float4v acc[4][4];
    #pragma unroll
    for (int i = 0; i < 4; ++i)
        #pragma unroll
        for (int j = 0; j < 4; ++j) acc[i][j] = (float4v)(0.f);

    for (int k0 = 0; k0 < 256; k0 += 32) {
        __syncthreads();
        #pragma unroll
        for (int h = 0; h < 2; ++h) {
            const float* src = h ? style : contentb;
            const int rb = h ? t0 : s0;
            short* dh = h ? Bh : Ah;
            short* dl = h ? Bl : Al;
            float v[16];
            #pragma unroll
            for (int j = 0; j < 16; ++j)
                v[j] = src[(size_t)(k0 + sl * 16 + j) * SP + rb + sm];
            short8 h0, h1, l0, l1;
            #pragma unroll
            for (int j = 0; j < 8; ++j) {
                unsigned ua = __float_as_uint(v[j]);
                unsigned ub = __float_as_uint(v[j + 8]);
                h0[j] = (short)(ua >> 16);
                h1[j] = (short)(ub >> 16);
                float ra  = v[j]     - __uint_as_float(ua & 0xffff0000u);
                float rb2 = v[j + 8] - __uint_as_float(ub & 0xffff0000u);
                l0[j] = (short)(__float_as_uint(ra) >> 16);
                l1[j] = (short)(__float_as_uint(rb2) >> 16);
            }
            // chunk = k/8: thread covers chunks sl*2 and sl*2+1
            *(short8*)(dh + ((sl * 2)     * 128 + sm) * 8) = h0;
            *(short8*)(dh + ((sl * 2 + 1) * 128 + sm) * 8) = h1;
            *(short8*)(dl + ((sl * 2)     * 128 + sm) * 8) = l0;
            *(short8*)(dl + ((sl * 2 + 1) * 128 + sm) * 8) = l1;
        }
        __syncthreads();

        short8 ah[4], al[4], bh[4], bl[4];
        #pragma unroll
        for (int f = 0; f < 4; ++f) {
            const int ra = (fq * 128 + wm + f * 16 + fr) * 8;
            const int rb = (fq * 128 + wn + f * 16 + fr) * 8;
            ah[f] = *(const short8*)(Ah + ra);
            al[f] = *(const short8*)(Al + ra);
            bh[f] = *(const short8*)(Bh + rb);
            bl[f] = *(const short8*)(Bl + rb);
        }
        #pragma unroll
        for (int fm = 0; fm < 4; ++fm)
            #pragma unroll
            for (int fn = 0; fn < 4; ++fn) {
                acc[fm][fn] = __builtin_amdgcn_mfma_f32_16x16x32_bf16(ah[fm], bh[fn], acc[fm][fn], 0, 0, 0);
                acc[fm][fn] = __builtin_amdgcn_mfma_f32_16x16x32_bf16(ah[fm], bl[fn], acc[fm][fn], 0, 0, 0);
                acc[fm][fn] = __builtin_amdgcn_mfma_f32_16x16x32_bf16(al[fm], bh[fn], acc[fm][fn], 0, 0, 0);
            }
    }

    // store: C/D layout col=lane&15, row=(lane>>4)*4+reg
    #pragma unroll
    for (int fm = 0; fm < 4; ++fm)
        #pragma unroll
        for (int fn = 0; fn < 4; ++fn)
            #pragma unroll
            for (int r = 0; r < 4; ++r) {
                unsigned u = __float_as_uint(acc[fm][fn][r]);
                unsigned short o = (unsigned short)((u + 0x7fffu + ((u >> 16) & 1u)) >> 16);
                Gb[(size_t)(s0 + wm + fm * 16 + fq * 4 + r) * SP + t0 + wn + fn * 16 + fr] = o;
            }
}

// ---------------------------------------------------------------------------
// Kernel 2: stencil feat[q][p] = sum_9 G[s+d][t+d] + enc_bias[p]; per-(q,ptile)
// top-2 packed keys -> cand. (unchanged from round 2, known good)
// ---------------------------------------------------------------------------
#define STP 209

__global__ __launch_bounds__(256) void stencil_cand(
    const unsigned short* __restrict__ Gb,
    const float* __restrict__ enc_bias,
    u64* __restrict__ cand, int b)
{
    __shared__ unsigned short Gt[100 * STP];
    __shared__ u64 Mrg[64 * 4 * 2];

    const int qT = blockIdx.x;
    const int pT = blockIdx.y;
    const int y0 = (qT >> 3) * 8, x0 = (qT & 7) * 8;
    const int ti0 = (pT >> 1) * 4, tj0 = (pT & 1) * 32;
    const int tid = threadIdx.x;

    for (int e = tid; e < 100 * 204; e += 256) {
        int s_l = e / 204; int te = e - s_l * 204;
        int ri = te / 34;  int cj = te - ri * 34;
        int sy = y0 + s_l / 10;
        int sx = x0 + (s_l - (s_l / 10) * 10);
        int ty = ti0 + ri, tx = tj0 + cj;
        if (sy < 64 && sx < 64 && ty < 64 && tx < 64)
            Gt[s_l * STP + te] = Gb[(size_t)(sy * 64 + sx) * SP + ty * 64 + tx];
    }
    __syncthreads();

    const int q_l = tid & 63, pq = tid >> 6;
    const int qy = q_l >> 3, qx = q_l & 7;
    const int y = y0 + qy, x = x0 + qx;
    const bool vq = (y < ND) && (x < ND);
    const int pi = ti0 + pq;
    const int base0 = (qy * 10 + qx) * STP + pq * 34;

    int OFF[9];
    #pragma unroll
    for (int u = 0; u < 3; ++u)
        #pragma unroll
        for (int v = 0; v < 3; ++v)
            OFF[u * 3 + v] = (u * 10 + v) * STP + u * 34 + v;

    u64 k1 = 0, k2 = 0;
    if (vq && pi < ND) {
        for (int pjl = 0; pjl < 32; ++pjl) {
            int pj = tj0 + pjl;
            if (pj >= ND) break;
            int base = base0 + pjl;
            float f = 0.f;
            #pragma unroll
            for (int d = 0; d < 9; ++d) f += bf2f(Gt[base + OFF[d]]);
            int p = pi * ND + pj;
            f += enc_bias[p];
            u64 key = ((u64)orderf(f) << 32) | (unsigned int)(NP - 1 - p);
            if (key > k1) { k2 = k1; k1 = key; }
            else if (key > k2) { k2 = key; }
        }
    }
    Mrg[(q_l * 4 + pq) * 2]     = k1;
    Mrg[(q_l * 4 + pq) * 2 + 1] = k2;
    __syncthreads();
    if (pq == 0 && vq) {
        u64 b1 = 0, b2 = 0;
        #pragma unroll
        for (int t = 0; t < 8; ++t) {
            u64 k = Mrg[q_l * 8 + t];
            if (k > b1) { b2 = b1; b1 = k; }
            else if (k > b2) { b2 = k; }
        }
        int q = y * ND + x;
        size_t o = ((size_t)(b * NP + q) * 32 + pT) * 2;
        cand[o] = b1; cand[o + 1] = b2;
    }
}

// ---------------------------------------------------------------------------
// Kernel 3: parallel top-2 pick + gap-skip + exact fp32 rescore.
// One block (128 thr = 2 waves) per (b,q). Wave w rescores cand w.
// ---------------------------------------------------------------------------
__global__ __launch_bounds__(128) void rescore2(
    const float* __restrict__ content,
    const float* __restrict__ style,     // [c][s] (fallback gather)
    const float* __restrict__ style_t,   // [s][c] or nullptr
    const float* __restrict__ enc_bias,
    const u64* __restrict__ cand,
    int* __restrict__ idx, int use_st)
{
    __shared__ float sc[2];
    __shared__ int   pp[2];
    const int qa = blockIdx.x;
    const int tid = threadIdx.x;
    const int wave = tid >> 6, lane = tid & 63;
    const int b = qa / NP, q = qa - b * NP;
    const int y = q / ND, x = q - y * ND;

    // --- top-2 scan (both waves redundantly; identical results) ---
    u64 k1 = cand[(size_t)qa * 64 + lane];
    u64 k2 = 0;
    #pragma unroll
    for (int d = 1; d < 64; d <<= 1) {
        u64 o1 = __shfl_xor(k1, d, 64);
        u64 o2 = __shfl_xor(k2, d, 64);
        u64 hi = k1 > o1 ? k1 : o1;
        u64 lo = k1 > o1 ? o1 : k1;
        u64 m2 = k2 > o2 ? k2 : o2;
        k1 = hi;
        k2 = lo > m2 ? lo : m2;
    }
    const int p1 = NP - 1 - (int)(k1 & 0xffffffffu);
    const int p2 = NP - 1 - (int)(k2 & 0xffffffffu);
    const float f1 = unorderf((unsigned int)(k1 >> 32));
    const float f2 = unorderf((unsigned int)(k2 >> 32));

    if (k2 == 0ull || (f1 - f2) > GAP_T) {   // provably safe skip
        if (tid == 0) idx[qa] = p1;
        return;
    }

    // --- exact fp32 dot for this wave's candidate ---
    const int pc = wave ? p2 : p1;
    const int pi = pc / ND, pj = pc - pi * ND;
    const int off_c = y * 64 + x;
    const int off_s = pi * 64 + pj;
    float s = 0.f;
    if (use_st) {
        #pragma unroll
        for (int g = 0; g < 4; ++g) {
            const int c = g * 64 + lane;
            const float* cw = content + ((size_t)b * NC + c) * SP + off_c;
            const float* sw = style_t + (size_t)off_s * 256 + c;
            #pragma unroll
            for (int u = 0; u < 3; ++u)
                #pragma unroll
                for (int v = 0; v < 3; ++v)
                    s = fmaf(cw[u * 64 + v], sw[(size_t)(u * 64 + v) * 256], s);
        }
    } else {
        #pragma unroll
        for (int g = 0; g < 4; ++g) {
            const int c = g * 64 + lane;
            const float* cw = content + ((size_t)b * NC + c) * SP + off_c;
            const float* sw = style + (size_t)c * SP + off_s;
            #pragma unroll
            for (int u = 0; u < 3; ++u)
                #pragma unroll
                for (int v = 0; v < 3; ++v)
                    s = fmaf(cw[u * 64 + v], sw[u * 64 + v], s);
        }
    }
    #pragma unroll
    for (int d = 32; d; d >>= 1) s += __shfl_xor(s, d, 64);
    if (lane == 0) { sc[wave] = s + enc_bias[pc]; pp[wave] = pc; }
    __syncthreads();
    if (tid == 0) {
        float s0 = sc[0], s1 = sc[1];
        int q0 = pp[0], q1 = pp[1];
        idx[qa] = (s1 > s0 || (s1 == s0 && q1 < q0)) ? q1 : q0;
    }
}

// ---------------------------------------------------------------------------
// Kernel 4b: output via style_t with LDS row accumulation.
// Block = (b,h) x c-half. orow[w][cl] accumulated with w-parity partition.
// ---------------------------------------------------------------------------
__global__ __launch_bounds__(256) void produce_out2(
    const float* __restrict__ style_t,
    const float* __restrict__ dec_bias,
    const float* __restrict__ intra_bias,
    const int* __restrict__ idx,
    float* __restrict__ out)
{
    __shared__ float orow[64][129];   // ~33 KB
    __shared__ int pidx[3][ND];

    const int bh = blockIdx.x;
    const int b = bh >> 6, h = bh & 63;
    const int ch = blockIdx.y;        // c-half (0/1)
    const int tid = threadIdx.x;

    if (tid < 3 * ND) {
        int u = tid / ND, xx = tid - u * ND;
        int yy = h - u;
        pidx[u][xx] = (yy >= 0 && yy < ND) ? idx[b * NP + yy * ND + xx] : 0;
    }
    for (int i = tid; i < 64 * 129; i += 256) ((float*)orow)[i] = 0.f;
    __syncthreads();

    const int cl = tid & 127;
    const int xo = tid >> 7;
    for (int u = 0; u < 3; ++u) {
        int yy = h - u;
        if (yy < 0 || yy >= ND) continue;   // uniform
        #pragma unroll
        for (int v = 0; v < 3; ++v) {
            // xi parity (xo+v)&1 => w=xi+v parity == xo : no cross-group RMW race
            for (int xi = (xo + v) & 1; xi < ND; xi += 2) {
                int p = pidx[u][xi];
                int pi = p / ND, pj = p - pi * ND;
                float sv = style_t[(size_t)(pi * 64 + pj + u * 64 + v) * 256 + ch * 128 + cl];
                orow[xi + v][cl] += sv;
            }
        }
    }
    __syncthreads();

    const int w = tid & 63, cg = tid >> 6;
    const int cu  = (h  < 2 ? h  : 2) - (h  > 61 ? h  - 61 : 0) + 1;
    const int cvw = (w  < 2 ? w  : 2) - (w  > 61 ? w  - 61 : 0) + 1;
    const float cnt = (float)(cu * cvw);
    #pragma unroll 4
    for (int ci = 0; ci < 32; ++ci) {
        int cll = cg * 32 + ci;
        int c = ch * 128 + cll;
        float val = (orow[w][cll] + dec_bias[c]) / (cnt + intra_bias[c]);
        out[(((size_t)b * NC + c) * 64 + h) * 64 + w] = val;
    }
}

// ---------------------------------------------------------------------------
// Kernel 4a: output via gather (mid-fallback; round-1 validated)
// ---------------------------------------------------------------------------
__global__ __launch_bounds__(256) void produce_out(
    const float* __restrict__ style,
    const float* __restrict__ dec_bias,
    const float* __restrict__ intra_bias,
    const int* __restrict__ idx,
    float* __restrict__ out)
{
    const int bh = blockIdx.x;
    const int b = bh >> 6;
    const int h = bh & 63;
    const int cg = blockIdx.y;
    const int tid = threadIdx.x;
    const int w = tid & 63;
    const int c = cg * 4 + (tid >> 6);

    __shared__ int pidx[3][ND];
    if (tid < 3 * ND) {
        int rr = tid / ND, jj = tid - rr * ND;
        int hh = h - 2 + rr;
        int p = 0;
        if (hh >= 0 && hh < ND) p = idx[b * NP + hh * ND + jj];
        pidx[rr][jj] = p;
    }
    __syncthreads();

    float s = 0.f;
    int cnt = 0;
    #pragma unroll
    for (int u = 0; u < 3; ++u) {
        int hh = h - u;
        if (hh < 0 || hh >= ND) continue;
        #pragma unroll
        for (int v = 0; v < 3; ++v) {
            int ww = w - v;
            if (ww < 0 || ww >= ND) continue;
            int p = pidx[2 - u][ww];
            int pi = p / ND, pj = p - pi * ND;
            s += style[(c * HW + pi + u) * HW + pj + v];
            cnt++;
        }
    }
    out[(((size_t)b * NC + c) * HW + h) * HW + w] =
        (s + dec_bias[c]) / ((float)cnt + intra_bias[c]);
}

// ---------------------------------------------------------------------------
// Deep fallback (round-1, known-good): fp32 VALU GEMM + argmax keys
// ---------------------------------------------------------------------------
#define FBK 16
#define FTM 64
#define FTN 128

__global__ __launch_bounds__(256) void init_keys(u64* keys) {
    int i = blockIdx.x * 256 + threadIdx.x;
    if (i < 4 * NP) keys[i] = 0ull;
}

__global__ __launch_bounds__(256) void feat_argmax(
    const float* __restrict__ content,
    const float* __restrict__ style,
    const float* __restrict__ enc_bias,
    u64* __restrict__ keys)
{
    __shared__ float As[FBK][FTM];
    __shared__ float Bs[FBK][FTN];
    __shared__ u64 red[FTM][16];

    const int tid = threadIdx.x;
    const int tx = tid & 15;
    const int ty = tid >> 4;
    const int b  = blockIdx.z;
    const int q0 = blockIdx.y * FTM;
    const int p0 = blockIdx.x * FTN;
    const float* __restrict__ cb = content + (size_t)b * NC * SP;

    const int mA = tid & 63;
    const int qA = q0 + mA;
    const bool vA = (qA < NP);
    int offA = 0;
    if (vA) { int y = qA / ND; int x = qA - y * ND; offA = y * HW + x; }
    const int kkA0 = tid >> 6;

    const int nB = tid & 127;
    const int pB = p0 + nB;
    const bool vB = (pB < NP);
    int offB = 0;
    if (vB) { int pi = pB / ND; int pj = pB - pi * ND; offB = pi * HW + pj; }
    const int kkB0 = tid >> 7;

    float acc[4][8];
    #pragma unroll
    for (int i = 0; i < 4; ++i)
        #pragma unroll
        for (int j = 0; j < 8; ++j) acc[i][j] = 0.f;

    for (int k0 = 0; k0 < KTOT; k0 += FBK) {
        #pragma unroll
        for (int j = 0; j < 4; ++j) {
            int kk = kkA0 + j * 4;
            int k = k0 + kk;
            int c = k / 9; int r = k - c * 9; int u = r / 3; int v = r - u * 3;
            float val = 0.f;
            if (vA) val = cb[c * SP + offA + u * HW + v];
            As[kk][mA] = val;
        }
        #pragma unroll
        for (int j = 0; j < 8; ++j) {
            int kk = kkB0 + j * 2;
            int k = k0 + kk;
            int c = k / 9; int r = k - c * 9; int u = r / 3; int v = r - u * 3;
            float val = 0.f;
            if (vB) val = style[c * SP + offB + u * HW + v];
            Bs[kk][nB] = val;
        }
        __syncthreads();
        #pragma unroll
        for (int kk = 0; kk < FBK; ++kk) {
            float a[4], bb[8];
            #pragma unroll
            for (int i = 0; i < 4; ++i) a[i] = As[kk][ty * 4 + i];
            #pragma unroll
            for (int j = 0; j < 8; ++j) bb[j] = Bs[kk][tx * 8 + j];
            #pragma unroll
            for (int i = 0; i < 4; ++i)
                #pragma unroll
                for (int j = 0; j < 8; ++j)
                    acc[i][j] = fmaf(a[i], bb[j], acc[i][j]);
        }
        __syncthreads();
    }

    float eb[8];
    #pragma unroll
    for (int j = 0; j < 8; ++j) {
        int p = p0 + tx * 8 + j;
        eb[j] = (p < NP) ? enc_bias[p] : 0.f;
    }
    #pragma unroll
    for (int i = 0; i < 4; ++i) {
        u64 best = 0ull;
        #pragma unroll
        for (int j = 0; j < 8; ++j) {
            int p = p0 + tx * 8 + j;
            if (p < NP) {
                float v = acc[i][j] + eb[j];
                u64 key = ((u64)orderf(v) << 32) | (unsigned int)(NP - 1 - p);
                best = best > key ? best : key;
            }
        }
        red[ty * 4 + i][tx] = best;
    }
    __syncthreads();
    if (tid < FTM) {
        u64 best = 0ull;
        #pragma unroll
        for (int t = 0; t < 16; ++t) {
            u64 k = red[tid][t];
            best = best > k ? best : k;
        }
        int q = q0 + tid;
        if (q < NP) atomicMax(&keys[(size_t)b * NP + q], best);
    }
}

__global__ __launch_bounds__(256) void key2idx(const u64* keys, int* idx) {
    int i = blockIdx.x * 256 + threadIdx.x;
    if (i < 4 * NP) idx[i] = NP - 1 - (int)(keys[i] & 0xffffffffu);
}

// ---------------------------------------------------------------------------
extern "C" void kernel_launch(void* const* d_in, const int* in_sizes, int n_in,
                              void* d_out, int out_size, void* d_ws, size_t ws_size,
                              hipStream_t stream) {
    const float* content    = (const float*)d_in[0];
    const float* style      = (const float*)d_in[1];
    const float* enc_bias   = (const float*)d_in[2];
    const float* dec_bias   = (const float*)d_in[3];
    const float* intra_bias = (const float*)d_in[4];
    float* out = (float*)d_out;

    const size_t G_BYTES    = (size_t)SP * SP * 2;            // 33,554,432
    const size_t CAND_BYTES = (size_t)4 * NP * 32 * 2 * 8;    //  1,968,128
    const size_t IDX_BYTES  = (size_t)4 * NP * 4;             //     61,504
    const size_t ST_BYTES   = (size_t)SP * NC * 4;            //  4,194,304
    const size_t NEED1 = G_BYTES + CAND_BYTES + IDX_BYTES;
    const size_t NEED2 = NEED1 + ST_BYTES;

    if (ws_size >= NEED1) {
        unsigned short* Gb = (unsigned short*)d_ws;
        u64* cand = (u64*)((char*)d_ws + G_BYTES);
        int* idx  = (int*)((char*)d_ws + G_BYTES + CAND_BYTES);
        float* style_t = (float*)((char*)d_ws + NEED1);
        const bool st = (ws_size >= NEED2);

        if (st)
            transpose_style<<<dim3(128, 8), 256, 0, stream>>>(style, style_t);
        for (int b = 0; b < 4; ++b) {
            g_gemm<<<dim3(32, 32), 256, 0, stream>>>(
                content + (size_t)b * NC * SP, style, Gb);
            stencil_cand<<<dim3(64, 32), 256, 0, stream>>>(
                Gb, enc_bias, cand, b);
        }
        rescore2<<<dim3(4 * NP), 128, 0, stream>>>(
            content, style, st ? style_t : nullptr, enc_bias, cand, idx, st ? 1 : 0);
        if (st)
            produce_out2<<<dim3(4 * 64, 2), 256, 0, stream>>>(
                style_t, dec_bias, intra_bias, idx, out);
        else
            produce_out<<<dim3(4 * 64, NC / 4), 256, 0, stream>>>(
                style, dec_bias, intra_bias, idx, out);
    } else {
        u64* keys = (u64*)d_ws;
        int* idx  = (int*)((char*)d_ws + (size_t)4 * NP * 8);
        init_keys<<<(4 * NP + 255) / 256, 256, 0, stream>>>(keys);
        feat_argmax<<<dim3((NP + FTN - 1) / FTN, (NP + FTM - 1) / FTM, 4), 256, 0, stream>>>(
            content, style, enc_bias, keys);
        key2idx<<<(4 * NP + 255) / 256, 256, 0, stream>>>(keys, idx);
        produce_out<<<dim3(4 * 64, NC / 4), 256, 0, stream>>>(
            style, dec_bias, intra_bias, idx, out);
    }
}

// Round 4
// 419.765 us; speedup vs baseline: 9.7936x; 1.6140x over previous
//
#include <hip/hip_runtime.h>
#include <stdint.h>

// Problem constants (B=4, C=256, H=W=64, PATCH=3, STRIDE=1)
#define NP   3844   // 62*62 patches == per-batch feat pixels
#define ND   62
#define NC   256
#define HW   64
#define SP   4096   // 64*64 pixels per image
#define KTOT 2304
#define GAP_T 6.0f  // > 2x worst-case bf16 screening error (9*0.25=2.25)

typedef __attribute__((ext_vector_type(8))) short short8;
typedef __attribute__((ext_vector_type(8))) unsigned short ushort8;
typedef __attribute__((ext_vector_type(4))) float float4v;
typedef unsigned long long u64;

__device__ __forceinline__ unsigned int orderf(float v) {
    unsigned int u = __float_as_uint(v);
    return (u & 0x80000000u) ? ~u : (u | 0x80000000u);
}
__device__ __forceinline__ float unorderf(unsigned int k) {
    return __uint_as_float((k & 0x80000000u) ? (k ^ 0x80000000u) : ~k);
}
__device__ __forceinline__ float bf2f(unsigned short h) {
    return __uint_as_float(((unsigned int)h) << 16);
}

// ---------------------------------------------------------------------------
// Kernel 0: style_t[s][c] = style[c][s]  (4 MB fp32, for coalesced c-reads)
// ---------------------------------------------------------------------------
__global__ __launch_bounds__(256) void transpose_style(
    const float* __restrict__ style, float* __restrict__ style_t)
{
    __shared__ float t[32][33];
    const int s0 = blockIdx.x * 32;
    const int c0 = blockIdx.y * 32;
    const int col = threadIdx.x & 31, r8 = threadIdx.x >> 5;
    #pragma unroll
    for (int i = 0; i < 4; ++i) {
        int r = r8 + i * 8;
        t[r][col] = style[(size_t)(c0 + r) * SP + s0 + col];
    }
    __syncthreads();
    #pragma unroll
    for (int i = 0; i < 4; ++i) {
        int r = r8 + i * 8;
        style_t[(size_t)(s0 + r) * 256 + c0 + col] = t[col][r];
    }
}

// ---------------------------------------------------------------------------
// Kernel 1: G[s][t] = sum_c content_b[c][s] * style[c][t], bf16x3-split MFMA.
// LDS layout: [k-chunk(4)][row(128)] of short8 -> 16B lane stride, 2-way free.
// (unchanged from round 3 — validated)
// ---------------------------------------------------------------------------
__global__ __launch_bounds__(256, 2) void g_gemm(
    const float* __restrict__ contentb,   // [256][4096] for this batch
    const float* __restrict__ style,      // [256][4096]
    unsigned short* __restrict__ Gb)      // [4096][4096] bf16
{
    __shared__ __attribute__((aligned(16))) short Ah[4 * 128 * 8];
    __shared__ __attribute__((aligned(16))) short Al[4 * 128 * 8];
    __shared__ __attribute__((aligned(16))) short Bh[4 * 128 * 8];
    __shared__ __attribute__((aligned(16))) short Bl[4 * 128 * 8];

    const int tid  = threadIdx.x;
    const int s0   = blockIdx.x * 128;
    const int t0   = blockIdx.y * 128;
    const int wave = tid >> 6, lane = tid & 63;
    const int wm = (wave >> 1) * 64, wn = (wave & 1) * 64;
    const int fr = lane & 15;   // frag row/col
    const int fq = lane >> 4;   // quad -> k-chunk

    const int sm = tid & 127;   // staging: row owner
    const int sl = tid >> 7;    // staging: k-half (0/1)

    float4v acc[4][4];
    #pragma unroll
    for (int i = 0; i < 4; ++i)
        #pragma unroll
        for (int j = 0; j < 4; ++j) acc[i][j] = (float4v)(0.f);

    for (int k0 = 0; k0 < 256; k0 += 32) {
        __syncthreads();
        #pragma unroll
        for (int h = 0; h < 2; ++h) {
            const float* src = h ? style : contentb;
            const int rb = h ? t0 : s0;
            short* dh = h ? Bh : Ah;
            short* dl = h ? Bl : Al;
            float v[16];
            #pragma unroll
            for (int j = 0; j < 16; ++j)
                v[j] = src[(size_t)(k0 + sl * 16 + j) * SP + rb + sm];
            short8 h0, h1, l0, l1;
            #pragma unroll
            for (int j = 0; j < 8; ++j) {
                unsigned ua = __float_as_uint(v[j]);
                unsigned ub = __float_as_uint(v[j + 8]);
                h0[j] = (short)(ua >> 16);
                h1[j] = (short)(ub >> 16);
                float ra  = v[j]     - __uint_as_float(ua & 0xffff0000u);
                float rb2 = v[j + 8] - __uint_as_float(ub & 0xffff0000u);
                l0[j] = (short)(__float_as_uint(ra) >> 16);
                l1[j] = (short)(__float_as_uint(rb2) >> 16);
            }
            *(short8*)(dh + ((sl * 2)     * 128 + sm) * 8) = h0;
            *(short8*)(dh + ((sl * 2 + 1) * 128 + sm) * 8) = h1;
            *(short8*)(dl + ((sl * 2)     * 128 + sm) * 8) = l0;
            *(short8*)(dl + ((sl * 2 + 1) * 128 + sm) * 8) = l1;
        }
        __syncthreads();

        short8 ah[4], al[4], bh[4], bl[4];
        #pragma unroll
        for (int f = 0; f < 4; ++f) {
            const int ra = (fq * 128 + wm + f * 16 + fr) * 8;
            const int rb = (fq * 128 + wn + f * 16 + fr) * 8;
            ah[f] = *(const short8*)(Ah + ra);
            al[f] = *(const short8*)(Al + ra);
            bh[f] = *(const short8*)(Bh + rb);
            bl[f] = *(const short8*)(Bl + rb);
        }
        #pragma unroll
        for (int fm = 0; fm < 4; ++fm)
            #pragma unroll
            for (int fn = 0; fn < 4; ++fn) {
                acc[fm][fn] = __builtin_amdgcn_mfma_f32_16x16x32_bf16(ah[fm], bh[fn], acc[fm][fn], 0, 0, 0);
                acc[fm][fn] = __builtin_amdgcn_mfma_f32_16x16x32_bf16(ah[fm], bl[fn], acc[fm][fn], 0, 0, 0);
                acc[fm][fn] = __builtin_amdgcn_mfma_f32_16x16x32_bf16(al[fm], bh[fn], acc[fm][fn], 0, 0, 0);
            }
    }

    // store: C/D layout col=lane&15, row=(lane>>4)*4+reg
    #pragma unroll
    for (int fm = 0; fm < 4; ++fm)
        #pragma unroll
        for (int fn = 0; fn < 4; ++fn)
            #pragma unroll
            for (int r = 0; r < 4; ++r) {
                unsigned u = __float_as_uint(acc[fm][fn][r]);
                unsigned short o = (unsigned short)((u + 0x7fffu + ((u >> 16) & 1u)) >> 16);
                Gb[(size_t)(s0 + wm + fm * 16 + fq * 4 + r) * SP + t0 + wn + fn * 16 + fr] = o;
            }
}

// ---------------------------------------------------------------------------
// Kernel 2 (NEW): direct-G vectorized stencil + global per-q top-2.
// One wave per q. Lane: ig = lane>>3 (i offset), jg = (lane&7)*8 (j group).
// feat[q][p] = sum_{u,v} G[(y+u)*64+x+v][(i+u)*64+j+v] + enc_bias[p].
// Aligned ushort8 + uint window loads; shift-extract in registers.
// No LDS tile, no barriers, no bank conflicts.
// ---------------------------------------------------------------------------
__global__ __launch_bounds__(256) void stencil_direct(
    const unsigned short* __restrict__ G,
    const float* __restrict__ enc_bias,
    u64* __restrict__ cand2, int b)
{
    const int q = blockIdx.x * 4 + (threadIdx.x >> 6);   // 961*4 = 3844 exact
    const int lane = threadIdx.x & 63;
    const int y = q / ND, x = q - y * ND;
    const int jg = (lane & 7) * 8;    // j0: 0..56
    const int ig = lane >> 3;         // i offset 0..7
    const unsigned short* Gq = G + (size_t)(y * 64 + x) * SP;

    u64 k1 = 0, k2 = 0;
    for (int it = 0; it < 8; ++it) {
        const int i = it * 8 + ig;
        if (i <= 61) {
            float f[8];
            #pragma unroll
            for (int j = 0; j < 8; ++j) f[j] = 0.f;
            #pragma unroll
            for (int u = 0; u < 3; ++u) {
                #pragma unroll
                for (int v = 0; v < 3; ++v) {
                    const unsigned short* rp =
                        Gq + (size_t)(u * 64 + v) * SP + (i + u) * 64 + jg;
                    ushort8 a = *(const ushort8*)rp;              // 16B aligned
                    unsigned e = (jg < 56) ? *(const unsigned*)(rp + 8) : 0u;
                    float w8 = bf2f((unsigned short)(e & 0xffffu));
                    float w9 = bf2f((unsigned short)(e >> 16));
                    if (v == 0) {
                        #pragma unroll
                        for (int j = 0; j < 8; ++j) f[j] += bf2f(a[j]);
                    } else if (v == 1) {
                        #pragma unroll
                        for (int j = 0; j < 7; ++j) f[j] += bf2f(a[j + 1]);
                        f[7] += w8;
                    } else {
                        #pragma unroll
                        for (int j = 0; j < 6; ++j) f[j] += bf2f(a[j + 2]);
                        f[6] += w8;
                        f[7] += w9;
                    }
                }
            }
            #pragma unroll
            for (int j = 0; j < 8; ++j) {
                int jj = jg + j;
                if (jj <= 61) {
                    int p = i * ND + jj;
                    float fv = f[j] + enc_bias[p];
                    u64 key = ((u64)orderf(fv) << 32) | (unsigned)(NP - 1 - p);
                    if (key > k1) { k2 = k1; k1 = key; }
                    else if (key > k2) k2 = key;
                }
            }
        }
    }

    // 64-lane butterfly: global top-2 of this q (validated pattern)
    #pragma unroll
    for (int d = 1; d < 64; d <<= 1) {
        u64 o1 = __shfl_xor(k1, d, 64);
        u64 o2 = __shfl_xor(k2, d, 64);
        u64 hi = k1 > o1 ? k1 : o1;
        u64 lo = k1 > o1 ? o1 : k1;
        u64 m2 = k2 > o2 ? k2 : o2;
        k1 = hi;
        k2 = lo > m2 ? lo : m2;
    }
    if (lane == 0) {
        size_t o = (size_t)(b * NP + q) * 2;
        cand2[o] = k1;
        cand2[o + 1] = k2;
    }
}

// ---------------------------------------------------------------------------
// Kernel 3: gap-skip + exact fp32 rescore of the two candidates.
// One block (2 waves) per (b,q); wave w rescores cand w. cand2 = 2 keys/q.
// ---------------------------------------------------------------------------
__global__ __launch_bounds__(128) void rescore3(
    const float* __restrict__ content,
    const float* __restrict__ style,     // [c][s] (fallback gather)
    const float* __restrict__ style_t,   // [s][c]
    const float* __restrict__ enc_bias,
    const u64* __restrict__ cand2,
    int* __restrict__ idx, int use_st)
{
    __shared__ float sc[2];
    __shared__ int   pp[2];
    const int qa = blockIdx.x;
    const int tid = threadIdx.x;
    const int wave = tid >> 6, lane = tid & 63;
    const int b = qa / NP, q = qa - b * NP;
    const int y = q / ND, x = q - y * ND;

    const u64 k1 = cand2[(size_t)qa * 2];
    const u64 k2 = cand2[(size_t)qa * 2 + 1];
    const int p1 = NP - 1 - (int)(k1 & 0xffffffffu);
    const int p2 = NP - 1 - (int)(k2 & 0xffffffffu);
    const float f1 = unorderf((unsigned int)(k1 >> 32));
    const float f2 = unorderf((unsigned int)(k2 >> 32));

    if (k2 == 0ull || (f1 - f2) > GAP_T) {   // provably safe skip
        if (tid == 0) idx[qa] = p1;
        return;
    }

    const int pc = wave ? p2 : p1;
    const int pi = pc / ND, pj = pc - pi * ND;
    const int off_c = y * 64 + x;
    const int off_s = pi * 64 + pj;
    float s = 0.f;
    if (use_st) {
        #pragma unroll
        for (int g = 0; g < 4; ++g) {
            const int c = g * 64 + lane;
            const float* cw = content + ((size_t)b * NC + c) * SP + off_c;
            const float* sw = style_t + (size_t)off_s * 256 + c;
            #pragma unroll
            for (int u = 0; u < 3; ++u)
                #pragma unroll
                for (int v = 0; v < 3; ++v)
                    s = fmaf(cw[u * 64 + v], sw[(size_t)(u * 64 + v) * 256], s);
        }
    } else {
        #pragma unroll
        for (int g = 0; g < 4; ++g) {
            const int c = g * 64 + lane;
            const float* cw = content + ((size_t)b * NC + c) * SP + off_c;
            const float* sw = style + (size_t)c * SP + off_s;
            #pragma unroll
            for (int u = 0; u < 3; ++u)
                #pragma unroll
                for (int v = 0; v < 3; ++v)
                    s = fmaf(cw[u * 64 + v], sw[u * 64 + v], s);
        }
    }
    #pragma unroll
    for (int d = 32; d; d >>= 1) s += __shfl_xor(s, d, 64);
    if (lane == 0) { sc[wave] = s + enc_bias[pc]; pp[wave] = pc; }
    __syncthreads();
    if (tid == 0) {
        float s0 = sc[0], s1 = sc[1];
        int q0 = pp[0], q1 = pp[1];
        idx[qa] = (s1 > s0 || (s1 == s0 && q1 < q0)) ? q1 : q0;
    }
}

// ---------------------------------------------------------------------------
// Kernel 4b: output via style_t with LDS row accumulation (round-3 validated)
// ---------------------------------------------------------------------------
__global__ __launch_bounds__(256) void produce_out2(
    const float* __restrict__ style_t,
    const float* __restrict__ dec_bias,
    const float* __restrict__ intra_bias,
    const int* __restrict__ idx,
    float* __restrict__ out)
{
    __shared__ float orow[64][129];
    __shared__ int pidx[3][ND];

    const int bh = blockIdx.x;
    const int b = bh >> 6, h = bh & 63;
    const int ch = blockIdx.y;        // c-half (0/1)
    const int tid = threadIdx.x;

    if (tid < 3 * ND) {
        int u = tid / ND, xx = tid - u * ND;
        int yy = h - u;
        pidx[u][xx] = (yy >= 0 && yy < ND) ? idx[b * NP + yy * ND + xx] : 0;
    }
    for (int i = tid; i < 64 * 129; i += 256) ((float*)orow)[i] = 0.f;
    __syncthreads();

    const int cl = tid & 127;
    const int xo = tid >> 7;
    for (int u = 0; u < 3; ++u) {
        int yy = h - u;
        if (yy < 0 || yy >= ND) continue;   // uniform
        #pragma unroll
        for (int v = 0; v < 3; ++v) {
            for (int xi = (xo + v) & 1; xi < ND; xi += 2) {
                int p = pidx[u][xi];
                int pi = p / ND, pj = p - pi * ND;
                float sv = style_t[(size_t)(pi * 64 + pj + u * 64 + v) * 256 + ch * 128 + cl];
                orow[xi + v][cl] += sv;
            }
        }
    }
    __syncthreads();

    const int w = tid & 63, cg = tid >> 6;
    const int cu  = (h < 2 ? h : 2) - (h > 61 ? h - 61 : 0) + 1;
    const int cvw = (w < 2 ? w : 2) - (w > 61 ? w - 61 : 0) + 1;
    const float cnt = (float)(cu * cvw);
    #pragma unroll 4
    for (int ci = 0; ci < 32; ++ci) {
        int cll = cg * 32 + ci;
        int c = ch * 128 + cll;
        float val = (orow[w][cll] + dec_bias[c]) / (cnt + intra_bias[c]);
        out[(((size_t)b * NC + c) * 64 + h) * 64 + w] = val;
    }
}

// ---------------------------------------------------------------------------
// Kernel 4a: output via gather (deep-fallback; round-1 validated)
// ---------------------------------------------------------------------------
__global__ __launch_bounds__(256) void produce_out(
    const float* __restrict__ style,
    const float* __restrict__ dec_bias,
    const float* __restrict__ intra_bias,
    const int* __restrict__ idx,
    float* __restrict__ out)
{
    const int bh = blockIdx.x;
    const int b = bh >> 6;
    const int h = bh & 63;
    const int cg = blockIdx.y;
    const int tid = threadIdx.x;
    const int w = tid & 63;
    const int c = cg * 4 + (tid >> 6);

    __shared__ int pidx[3][ND];
    if (tid < 3 * ND) {
        int rr = tid / ND, jj = tid - rr * ND;
        int hh = h - 2 + rr;
        int p = 0;
        if (hh >= 0 && hh < ND) p = idx[b * NP + hh * ND + jj];
        pidx[rr][jj] = p;
    }
    __syncthreads();

    float s = 0.f;
    int cnt = 0;
    #pragma unroll
    for (int u = 0; u < 3; ++u) {
        int hh = h - u;
        if (hh < 0 || hh >= ND) continue;
        #pragma unroll
        for (int v = 0; v < 3; ++v) {
            int ww = w - v;
            if (ww < 0 || ww >= ND) continue;
            int p = pidx[2 - u][ww];
            int pi = p / ND, pj = p - pi * ND;
            s += style[(c * HW + pi + u) * HW + pj + v];
            cnt++;
        }
    }
    out[(((size_t)b * NC + c) * HW + h) * HW + w] =
        (s + dec_bias[c]) / ((float)cnt + intra_bias[c]);
}

// ---------------------------------------------------------------------------
// Deep fallback (round-1, known-good): fp32 VALU GEMM + argmax keys
// ---------------------------------------------------------------------------
#define FBK 16
#define FTM 64
#define FTN 128

__global__ __launch_bounds__(256) void init_keys(u64* keys) {
    int i = blockIdx.x * 256 + threadIdx.x;
    if (i < 4 * NP) keys[i] = 0ull;
}

__global__ __launch_bounds__(256) void feat_argmax(
    const float* __restrict__ content,
    const float* __restrict__ style,
    const float* __restrict__ enc_bias,
    u64* __restrict__ keys)
{
    __shared__ float As[FBK][FTM];
    __shared__ float Bs[FBK][FTN];
    __shared__ u64 red[FTM][16];

    const int tid = threadIdx.x;
    const int tx = tid & 15;
    const int ty = tid >> 4;
    const int b  = blockIdx.z;
    const int q0 = blockIdx.y * FTM;
    const int p0 = blockIdx.x * FTN;
    const float* __restrict__ cb = content + (size_t)b * NC * SP;

    const int mA = tid & 63;
    const int qA = q0 + mA;
    const bool vA = (qA < NP);
    int offA = 0;
    if (vA) { int y = qA / ND; int x = qA - y * ND; offA = y * HW + x; }
    const int kkA0 = tid >> 6;

    const int nB = tid & 127;
    const int pB = p0 + nB;
    const bool vB = (pB < NP);
    int offB = 0;
    if (vB) { int pi = pB / ND; int pj = pB - pi * ND; offB = pi * HW + pj; }
    const int kkB0 = tid >> 7;

    float acc[4][8];
    #pragma unroll
    for (int i = 0; i < 4; ++i)
        #pragma unroll
        for (int j = 0; j < 8; ++j) acc[i][j] = 0.f;

    for (int k0 = 0; k0 < KTOT; k0 += FBK) {
        #pragma unroll
        for (int j = 0; j < 4; ++j) {
            int kk = kkA0 + j * 4;
            int k = k0 + kk;
            int c = k / 9; int r = k - c * 9; int u = r / 3; int v = r - u * 3;
            float val = 0.f;
            if (vA) val = cb[c * SP + offA + u * HW + v];
            As[kk][mA] = val;
        }
        #pragma unroll
        for (int j = 0; j < 8; ++j) {
            int kk = kkB0 + j * 2;
            int k = k0 + kk;
            int c = k / 9; int r = k - c * 9; int u = r / 3; int v = r - u * 3;
            float val = 0.f;
            if (vB) val = style[c * SP + offB + u * HW + v];
            Bs[kk][nB] = val;
        }
        __syncthreads();
        #pragma unroll
        for (int kk = 0; kk < FBK; ++kk) {
            float a[4], bb[8];
            #pragma unroll
            for (int i = 0; i < 4; ++i) a[i] = As[kk][ty * 4 + i];
            #pragma unroll
            for (int j = 0; j < 8; ++j) bb[j] = Bs[kk][tx * 8 + j];
            #pragma unroll
            for (int i = 0; i < 4; ++i)
                #pragma unroll
                for (int j = 0; j < 8; ++j)
                    acc[i][j] = fmaf(a[i], bb[j], acc[i][j]);
        }
        __syncthreads();
    }

    float eb[8];
    #pragma unroll
    for (int j = 0; j < 8; ++j) {
        int p = p0 + tx * 8 + j;
        eb[j] = (p < NP) ? enc_bias[p] : 0.f;
    }
    #pragma unroll
    for (int i = 0; i < 4; ++i) {
        u64 best = 0ull;
        #pragma unroll
        for (int j = 0; j < 8; ++j) {
            int p = p0 + tx * 8 + j;
            if (p < NP) {
                float v = acc[i][j] + eb[j];
                u64 key = ((u64)orderf(v) << 32) | (unsigned int)(NP - 1 - p);
                best = best > key ? best : key;
            }
        }
        red[ty * 4 + i][tx] = best;
    }
    __syncthreads();
    if (tid < FTM) {
        u64 best = 0ull;
        #pragma unroll
        for (int t = 0; t < 16; ++t) {
            u64 k = red[tid][t];
            best = best > k ? best : k;
        }
        int q = q0 + tid;
        if (q < NP) atomicMax(&keys[(size_t)b * NP + q], best);
    }
}

__global__ __launch_bounds__(256) void key2idx(const u64* keys, int* idx) {
    int i = blockIdx.x * 256 + threadIdx.x;
    if (i < 4 * NP) idx[i] = NP - 1 - (int)(keys[i] & 0xffffffffu);
}

// ---------------------------------------------------------------------------
extern "C" void kernel_launch(void* const* d_in, const int* in_sizes, int n_in,
                              void* d_out, int out_size, void* d_ws, size_t ws_size,
                              hipStream_t stream) {
    const float* content    = (const float*)d_in[0];
    const float* style      = (const float*)d_in[1];
    const float* enc_bias   = (const float*)d_in[2];
    const float* dec_bias   = (const float*)d_in[3];
    const float* intra_bias = (const float*)d_in[4];
    float* out = (float*)d_out;

    const size_t G_BYTES     = (size_t)SP * SP * 2;        // 33,554,432
    const size_t CAND2_BYTES = (size_t)4 * NP * 2 * 8;     //    246,016
    const size_t IDX_BYTES   = (size_t)4 * NP * 4;         //     61,504
    const size_t ST_BYTES    = (size_t)SP * NC * 4;        //  4,194,304
    const size_t OFF_CAND2 = G_BYTES;
    const size_t OFF_IDX   = OFF_CAND2 + CAND2_BYTES;
    const size_t OFF_ST    = OFF_IDX + IDX_BYTES;          // 64B-aligned
    const size_t NEED = OFF_ST + ST_BYTES;                 // 38,056,256

    if (ws_size >= NEED) {
        unsigned short* Gb = (unsigned short*)d_ws;
        u64* cand2     = (u64*)((char*)d_ws + OFF_CAND2);
        int* idx       = (int*)((char*)d_ws + OFF_IDX);
        float* style_t = (float*)((char*)d_ws + OFF_ST);

        transpose_style<<<dim3(128, 8), 256, 0, stream>>>(style, style_t);
        for (int b = 0; b < 4; ++b) {
            g_gemm<<<dim3(32, 32), 256, 0, stream>>>(
                content + (size_t)b * NC * SP, style, Gb);
            stencil_direct<<<dim3(NP / 4), 256, 0, stream>>>(
                Gb, enc_bias, cand2, b);
        }
        rescore3<<<dim3(4 * NP), 128, 0, stream>>>(
            content, style, style_t, enc_bias, cand2, idx, 1);
        produce_out2<<<dim3(4 * 64, 2), 256, 0, stream>>>(
            style_t, dec_bias, intra_bias, idx, out);
    } else {
        u64* keys = (u64*)d_ws;
        int* idx  = (int*)((char*)d_ws + (size_t)4 * NP * 8);
        init_keys<<<(4 * NP + 255) / 256, 256, 0, stream>>>(keys);
        feat_argmax<<<dim3((NP + FTN - 1) / FTN, (NP + FTM - 1) / FTM, 4), 256, 0, stream>>>(
            content, style, enc_bias, keys);
        key2idx<<<(4 * NP + 255) / 256, 256, 0, stream>>>(keys, idx);
        produce_out<<<dim3(4 * 64, NC / 4), 256, 0, stream>>>(
            style, dec_bias, intra_bias, idx, out);
    }
}

// Round 5
// 401.416 us; speedup vs baseline: 10.2413x; 1.0457x over previous
//
#include <hip/hip_runtime.h>
#include <stdint.h>

// Problem constants (B=4, C=256, H=W=64, PATCH=3, STRIDE=1)
#define NP   3844   // 62*62 patches == per-batch feat pixels
#define ND   62
#define NC   256
#define HW   64
#define SP   4096   // 64*64 pixels per image
#define EPS_G 0.5f  // margin for gemm-internal (split/accum) error

typedef __attribute__((ext_vector_type(8))) short short8;
typedef __attribute__((ext_vector_type(8))) unsigned short ushort8;
typedef __attribute__((ext_vector_type(4))) float float4v;
typedef unsigned long long u64;

__device__ __forceinline__ unsigned int orderf(float v) {
    unsigned int u = __float_as_uint(v);
    return (u & 0x80000000u) ? ~u : (u | 0x80000000u);
}
__device__ __forceinline__ float unorderf(unsigned int k) {
    return __uint_as_float((k & 0x80000000u) ? (k ^ 0x80000000u) : ~k);
}
__device__ __forceinline__ float bf2f(unsigned short h) {
    return __uint_as_float(((unsigned int)h) << 16);
}
__device__ __forceinline__ unsigned short f2bf_rne(float a) {
    unsigned ua = __float_as_uint(a);
    return (unsigned short)((ua + 0x7fffu + ((ua >> 16) & 1u)) >> 16);
}

// ---------------------------------------------------------------------------
// Kernel 0: style_t[s][c] = style[c][s]  (4 MB fp32, for coalesced c-reads)
// ---------------------------------------------------------------------------
__global__ __launch_bounds__(256) void transpose_style(
    const float* __restrict__ style, float* __restrict__ style_t)
{
    __shared__ float t[32][33];
    const int s0 = blockIdx.x * 32;
    const int c0 = blockIdx.y * 32;
    const int col = threadIdx.x & 31, r8 = threadIdx.x >> 5;
    #pragma unroll
    for (int i = 0; i < 4; ++i) {
        int r = r8 + i * 8;
        t[r][col] = style[(size_t)(c0 + r) * SP + s0 + col];
    }
    __syncthreads();
    #pragma unroll
    for (int i = 0; i < 4; ++i) {
        int r = r8 + i * 8;
        style_t[(size_t)(s0 + r) * 256 + c0 + col] = t[col][r];
    }
}

// ---------------------------------------------------------------------------
// Kernel 0b (NEW): fp32 [256][4096] -> bf16 hi/lo in k-panel layout
// P[kp][s][j] with kp=k/8, j=k%8: one MFMA fragment = ushort8 at ((kp*4096+s)*8).
// ---------------------------------------------------------------------------
__global__ __launch_bounds__(256) void split_panels(
    const float* __restrict__ src,        // [256][4096]
    unsigned short* __restrict__ Phi,
    unsigned short* __restrict__ Plo)
{
    __shared__ unsigned short hbuf[512 * 8];
    __shared__ unsigned short lbuf[512 * 8];
    const int kp = blockIdx.x;            // 0..31
    const int s0 = blockIdx.y * 512;      // 0..7
    const int tid = threadIdx.x;
    #pragma unroll
    for (int kk = 0; kk < 8; ++kk) {
        #pragma unroll
        for (int h = 0; h < 2; ++h) {
            int s = tid + h * 256;
            float a = src[(size_t)(kp * 8 + kk) * SP + s0 + s];
            unsigned short hi = f2bf_rne(a);
            float r = a - bf2f(hi);       // exact in fp32
            unsigned short lo = f2bf_rne(r);
            hbuf[s * 8 + kk] = hi;
            lbuf[s * 8 + kk] = lo;
        }
    }
    __syncthreads();
    #pragma unroll
    for (int h = 0; h < 2; ++h) {
        int s = tid + h * 256;
        size_t o = ((size_t)kp * 4096 + s0 + s) * 8;
        *(ushort8*)(Phi + o) = *(const ushort8*)(hbuf + s * 8);
        *(ushort8*)(Plo + o) = *(const ushort8*)(lbuf + s * 8);
    }
}

// ---------------------------------------------------------------------------
// Kernel 1 (NEW): panel GEMM — G = content^T * style via bf16x3 MFMA.
// Fragments loaded DIRECTLY from L2 (pre-split panels). No LDS, no barriers.
// ---------------------------------------------------------------------------
__global__ __launch_bounds__(256) void g_gemm_p(
    const unsigned short* __restrict__ Ahi, const unsigned short* __restrict__ Alo,
    const unsigned short* __restrict__ Bhi, const unsigned short* __restrict__ Blo,
    unsigned short* __restrict__ Gb)
{
    const int tid  = threadIdx.x;
    const int s0   = blockIdx.x * 128;
    const int t0   = blockIdx.y * 128;
    const int wave = tid >> 6, lane = tid & 63;
    const int wm = (wave >> 1) * 64, wn = (wave & 1) * 64;
    const int fr = lane & 15;
    const int fq = lane >> 4;     // k-quad -> panel offset

    float4v acc[4][4];
    #pragma unroll
    for (int i = 0; i < 4; ++i)
        #pragma unroll
        for (int j = 0; j < 4; ++j) acc[i][j] = (float4v)(0.f);

    size_t ra0[4], rb0[4];
    #pragma unroll
    for (int f = 0; f < 4; ++f) {
        ra0[f] = ((size_t)fq * 4096 + s0 + wm + f * 16 + fr) * 8;
        rb0[f] = ((size_t)fq * 4096 + t0 + wn + f * 16 + fr) * 8;
    }

    #pragma unroll 2
    for (int kq0 = 0; kq0 < 32; kq0 += 4) {
        const size_t pan = (size_t)kq0 * 4096 * 8;
        short8 ah[4], al[4], bh[4], bl[4];
        #pragma unroll
        for (int f = 0; f < 4; ++f) {
            ah[f] = *(const short8*)(Ahi + pan + ra0[f]);
            al[f] = *(const short8*)(Alo + pan + ra0[f]);
            bh[f] = *(const short8*)(Bhi + pan + rb0[f]);
            bl[f] = *(const short8*)(Blo + pan + rb0[f]);
        }
        #pragma unroll
        for (int fm = 0; fm < 4; ++fm)
            #pragma unroll
            for (int fn = 0; fn < 4; ++fn) {
                acc[fm][fn] = __builtin_amdgcn_mfma_f32_16x16x32_bf16(ah[fm], bh[fn], acc[fm][fn], 0, 0, 0);
                acc[fm][fn] = __builtin_amdgcn_mfma_f32_16x16x32_bf16(ah[fm], bl[fn], acc[fm][fn], 0, 0, 0);
                acc[fm][fn] = __builtin_amdgcn_mfma_f32_16x16x32_bf16(al[fm], bh[fn], acc[fm][fn], 0, 0, 0);
            }
    }

    // store: C/D layout col=lane&15, row=(lane>>4)*4+reg  (validated)
    #pragma unroll
    for (int fm = 0; fm < 4; ++fm)
        #pragma unroll
        for (int fn = 0; fn < 4; ++fn)
            #pragma unroll
            for (int r = 0; r < 4; ++r) {
                unsigned short o = f2bf_rne(acc[fm][fn][r]);
                Gb[(size_t)(s0 + wm + fm * 16 + fq * 4 + r) * SP + t0 + wn + fn * 16 + fr] = o;
            }
}

// ---------------------------------------------------------------------------
// Kernel 1-fallback (round-3/4 validated): LDS-staged split GEMM
// ---------------------------------------------------------------------------
__global__ __launch_bounds__(256, 2) void g_gemm(
    const float* __restrict__ contentb,
    const float* __restrict__ style,
    unsigned short* __restrict__ Gb)
{
    __shared__ __attribute__((aligned(16))) short Ah[4 * 128 * 8];
    __shared__ __attribute__((aligned(16))) short Al[4 * 128 * 8];
    __shared__ __attribute__((aligned(16))) short Bh[4 * 128 * 8];
    __shared__ __attribute__((aligned(16))) short Bl[4 * 128 * 8];

    const int tid  = threadIdx.x;
    const int s0   = blockIdx.x * 128;
    const int t0   = blockIdx.y * 128;
    const int wave = tid >> 6, lane = tid & 63;
    const int wm = (wave >> 1) * 64, wn = (wave & 1) * 64;
    const int fr = lane & 15;
    const int fq = lane >> 4;
    const int sm = tid & 127;
    const int sl = tid >> 7;

    float4v acc[4][4];
    #pragma unroll
    for (int i = 0; i < 4; ++i)
        #pragma unroll
        for (int j = 0; j < 4; ++j) acc[i][j] = (float4v)(0.f);

    for (int k0 = 0; k0 < 256; k0 += 32) {
        __syncthreads();
        #pragma unroll
        for (int h = 0; h < 2; ++h) {
            const float* src = h ? style : contentb;
            const int rb = h ? t0 : s0;
            short* dh = h ? Bh : Ah;
            short* dl = h ? Bl : Al;
            float v[16];
            #pragma unroll
            for (int j = 0; j < 16; ++j)
                v[j] = src[(size_t)(k0 + sl * 16 + j) * SP + rb + sm];
            short8 h0, h1, l0, l1;
            #pragma unroll
            for (int j = 0; j < 8; ++j) {
                unsigned ua = __float_as_uint(v[j]);
                unsigned ub = __float_as_uint(v[j + 8]);
                h0[j] = (short)(ua >> 16);
                h1[j] = (short)(ub >> 16);
                float ra  = v[j]     - __uint_as_float(ua & 0xffff0000u);
                float rb2 = v[j + 8] - __uint_as_float(ub & 0xffff0000u);
                l0[j] = (short)(__float_as_uint(ra) >> 16);
                l1[j] = (short)(__float_as_uint(rb2) >> 16);
            }
            *(short8*)(dh + ((sl * 2)     * 128 + sm) * 8) = h0;
            *(short8*)(dh + ((sl * 2 + 1) * 128 + sm) * 8) = h1;
            *(short8*)(dl + ((sl * 2)     * 128 + sm) * 8) = l0;
            *(short8*)(dl + ((sl * 2 + 1) * 128 + sm) * 8) = l1;
        }
        __syncthreads();

        short8 ah[4], al[4], bh[4], bl[4];
        #pragma unroll
        for (int f = 0; f < 4; ++f) {
            const int ra = (fq * 128 + wm + f * 16 + fr) * 8;
            const int rb = (fq * 128 + wn + f * 16 + fr) * 8;
            ah[f] = *(const short8*)(Ah + ra);
            al[f] = *(const short8*)(Al + ra);
            bh[f] = *(const short8*)(Bh + rb);
            bl[f] = *(const short8*)(Bl + rb);
        }
        #pragma unroll
        for (int fm = 0; fm < 4; ++fm)
            #pragma unroll
            for (int fn = 0; fn < 4; ++fn) {
                acc[fm][fn] = __builtin_amdgcn_mfma_f32_16x16x32_bf16(ah[fm], bh[fn], acc[fm][fn], 0, 0, 0);
                acc[fm][fn] = __builtin_amdgcn_mfma_f32_16x16x32_bf16(ah[fm], bl[fn], acc[fm][fn], 0, 0, 0);
                acc[fm][fn] = __builtin_amdgcn_mfma_f32_16x16x32_bf16(al[fm], bh[fn], acc[fm][fn], 0, 0, 0);
            }
    }

    #pragma unroll
    for (int fm = 0; fm < 4; ++fm)
        #pragma unroll
        for (int fn = 0; fn < 4; ++fn)
            #pragma unroll
            for (int r = 0; r < 4; ++r) {
                unsigned short o = f2bf_rne(acc[fm][fn][r]);
                Gb[(size_t)(s0 + wm + fm * 16 + fq * 4 + r) * SP + t0 + wn + fn * 16 + fr] = o;
            }
}

// ---------------------------------------------------------------------------
// Kernel 2: direct-G vectorized stencil + global per-q top-2 (round-4 validated)
// ---------------------------------------------------------------------------
__global__ __launch_bounds__(256) void stencil_direct(
    const unsigned short* __restrict__ G,
    const float* __restrict__ enc_bias,
    u64* __restrict__ cand2, int b)
{
    const int q = blockIdx.x * 4 + (threadIdx.x >> 6);
    const int lane = threadIdx.x & 63;
    const int y = q / ND, x = q - y * ND;
    const int jg = (lane & 7) * 8;
    const int ig = lane >> 3;
    const unsigned short* Gq = G + (size_t)(y * 64 + x) * SP;

    u64 k1 = 0, k2 = 0;
    for (int it = 0; it < 8; ++it) {
        const int i = it * 8 + ig;
        if (i <= 61) {
            float f[8];
            #pragma unroll
            for (int j = 0; j < 8; ++j) f[j] = 0.f;
            #pragma unroll
            for (int u = 0; u < 3; ++u) {
                #pragma unroll
                for (int v = 0; v < 3; ++v) {
                    const unsigned short* rp =
                        Gq + (size_t)(u * 64 + v) * SP + (i + u) * 64 + jg;
                    ushort8 a = *(const ushort8*)rp;
                    unsigned e = (jg < 56) ? *(const unsigned*)(rp + 8) : 0u;
                    float w8 = bf2f((unsigned short)(e & 0xffffu));
                    float w9 = bf2f((unsigned short)(e >> 16));
                    if (v == 0) {
                        #pragma unroll
                        for (int j = 0; j < 8; ++j) f[j] += bf2f(a[j]);
                    } else if (v == 1) {
                        #pragma unroll
                        for (int j = 0; j < 7; ++j) f[j] += bf2f(a[j + 1]);
                        f[7] += w8;
                    } else {
                        #pragma unroll
                        for (int j = 0; j < 6; ++j) f[j] += bf2f(a[j + 2]);
                        f[6] += w8;
                        f[7] += w9;
                    }
                }
            }
            #pragma unroll
            for (int j = 0; j < 8; ++j) {
                int jj = jg + j;
                if (jj <= 61) {
                    int p = i * ND + jj;
                    float fv = f[j] + enc_bias[p];
                    u64 key = ((u64)orderf(fv) << 32) | (unsigned)(NP - 1 - p);
                    if (key > k1) { k2 = k1; k1 = key; }
                    else if (key > k2) k2 = key;
                }
            }
        }
    }

    #pragma unroll
    for (int d = 1; d < 64; d <<= 1) {
        u64 o1 = __shfl_xor(k1, d, 64);
        u64 o2 = __shfl_xor(k2, d, 64);
        u64 hi = k1 > o1 ? k1 : o1;
        u64 lo = k1 > o1 ? o1 : k1;
        u64 m2 = k2 > o2 ? k2 : o2;
        k1 = hi;
        k2 = lo > m2 ? lo : m2;
    }
    if (lane == 0) {
        size_t o = (size_t)(b * NP + q) * 2;
        cand2[o] = k1;
        cand2[o + 1] = k2;
    }
}

// ---------------------------------------------------------------------------
// Kernel 3: per-candidate ulp-sum error bound + gap-skip + exact fp32 rescore.
// ---------------------------------------------------------------------------
__global__ __launch_bounds__(128) void rescore3(
    const float* __restrict__ content,
    const float* __restrict__ style_t,   // [s][c]
    const float* __restrict__ enc_bias,
    const unsigned short* __restrict__ G,
    const u64* __restrict__ cand2,
    int* __restrict__ idx)
{
    __shared__ float sc[2];
    __shared__ int   pp[2];
    const int qa = blockIdx.x;
    const int tid = threadIdx.x;
    const int wave = tid >> 6, lane = tid & 63;
    const int b = qa / NP, q = qa - b * NP;
    const int y = q / ND, x = q - y * ND;

    const u64 k1 = cand2[(size_t)qa * 2];
    const u64 k2 = cand2[(size_t)qa * 2 + 1];
    const int p1 = NP - 1 - (int)(k1 & 0xffffffffu);
    const int p2 = NP - 1 - (int)(k2 & 0xffffffffu);
    const float f1 = unorderf((unsigned int)(k1 >> 32));
    const float f2 = unorderf((unsigned int)(k2 >> 32));

    if (k2 == 0ull) {
        if (tid == 0) idx[qa] = p1;
        return;
    }

    // data-dependent screening-error bound: E = sum_9 ulp(G_d) per candidate
    float eul = 0.f;
    {
        const int side = lane >> 4;            // lanes 0-8 -> p1, 16-24 -> p2
        const int d = lane & 15;
        if (side < 2 && d < 9) {
            int u = d / 3, v = d - u * 3;
            int pc = side ? p2 : p1;
            int pi = pc / ND, pj = pc - pi * ND;
            unsigned short g = G[(size_t)((y + u) * 64 + x + v) * SP
                                 + (pi + u) * 64 + pj + v];
            float gf = bf2f(g);
            eul = __uint_as_float(__float_as_uint(gf) & 0x7f800000u) * 0.0078125f;
        }
    }
    #pragma unroll
    for (int d = 1; d < 64; d <<= 1) eul += __shfl_xor(eul, d, 64);
    // eul now = E(p1) + E(p2) on every lane

    if ((f1 - f2) > eul + EPS_G) {
        if (tid == 0) idx[qa] = p1;
        return;
    }

    const int pc = wave ? p2 : p1;
    const int pi = pc / ND, pj = pc - pi * ND;
    const int off_c = y * 64 + x;
    const int off_s = pi * 64 + pj;
    float s = 0.f;
    #pragma unroll
    for (int g = 0; g < 4; ++g) {
        const int c = g * 64 + lane;
        const float* cw = content + ((size_t)b * NC + c) * SP + off_c;
        const float* sw = style_t + (size_t)off_s * 256 + c;
        #pragma unroll
        for (int u = 0; u < 3; ++u)
            #pragma unroll
            for (int v = 0; v < 3; ++v)
                s = fmaf(cw[u * 64 + v], sw[(size_t)(u * 64 + v) * 256], s);
    }
    #pragma unroll
    for (int d = 32; d; d >>= 1) s += __shfl_xor(s, d, 64);
    if (lane == 0) { sc[wave] = s + enc_bias[pc]; pp[wave] = pc; }
    __syncthreads();
    if (tid == 0) {
        float s0 = sc[0], s1 = sc[1];
        int q0 = pp[0], q1 = pp[1];
        idx[qa] = (s1 > s0 || (s1 == s0 && q1 < q0)) ? q1 : q0;
    }
}

// ---------------------------------------------------------------------------
// Kernel 4: output via style_t with LDS row accumulation (round-3/4 validated)
// ---------------------------------------------------------------------------
__global__ __launch_bounds__(256) void produce_out2(
    const float* __restrict__ style_t,
    const float* __restrict__ dec_bias,
    const float* __restrict__ intra_bias,
    const int* __restrict__ idx,
    float* __restrict__ out)
{
    __shared__ float orow[64][129];
    __shared__ int pidx[3][ND];

    const int bh = blockIdx.x;
    const int b = bh >> 6, h = bh & 63;
    const int ch = blockIdx.y;
    const int tid = threadIdx.x;

    if (tid < 3 * ND) {
        int u = tid / ND, xx = tid - u * ND;
        int yy = h - u;
        pidx[u][xx] = (yy >= 0 && yy < ND) ? idx[b * NP + yy * ND + xx] : 0;
    }
    for (int i = tid; i < 64 * 129; i += 256) ((float*)orow)[i] = 0.f;
    __syncthreads();

    const int cl = tid & 127;
    const int xo = tid >> 7;
    for (int u = 0; u < 3; ++u) {
        int yy = h - u;
        if (yy < 0 || yy >= ND) continue;
        #pragma unroll
        for (int v = 0; v < 3; ++v) {
            for (int xi = (xo + v) & 1; xi < ND; xi += 2) {
                int p = pidx[u][xi];
                int pi = p / ND, pj = p - pi * ND;
                float sv = style_t[(size_t)(pi * 64 + pj + u * 64 + v) * 256 + ch * 128 + cl];
                orow[xi + v][cl] += sv;
            }
        }
    }
    __syncthreads();

    const int w = tid & 63, cg = tid >> 6;
    const int cu  = (h < 2 ? h : 2) - (h > 61 ? h - 61 : 0) + 1;
    const int cvw = (w < 2 ? w : 2) - (w > 61 ? w - 61 : 0) + 1;
    const float cnt = (float)(cu * cvw);
    #pragma unroll 4
    for (int ci = 0; ci < 32; ++ci) {
        int cll = cg * 32 + ci;
        int c = ch * 128 + cll;
        float val = (orow[w][cll] + dec_bias[c]) / (cnt + intra_bias[c]);
        out[(((size_t)b * NC + c) * 64 + h) * 64 + w] = val;
    }
}

// ---------------------------------------------------------------------------
extern "C" void kernel_launch(void* const* d_in, const int* in_sizes, int n_in,
                              void* d_out, int out_size, void* d_ws, size_t ws_size,
                              hipStream_t stream) {
    const float* content    = (const float*)d_in[0];
    const float* style      = (const float*)d_in[1];
    const float* enc_bias   = (const float*)d_in[2];
    const float* dec_bias   = (const float*)d_in[3];
    const float* intra_bias = (const float*)d_in[4];
    float* out = (float*)d_out;

    const size_t G_BYTES     = (size_t)SP * SP * 2;        // 33,554,432
    const size_t CAND2_BYTES = (size_t)4 * NP * 2 * 8;     //    246,016
    const size_t IDX_BYTES   = (size_t)4 * NP * 4;         //     61,504
    const size_t ST_BYTES    = (size_t)SP * NC * 4;        //  4,194,304
    const size_t PS_BYTES    = (size_t)NC * SP * 2;        //  2,097,152 (one split array)
    const size_t OFF_CAND2 = G_BYTES;
    const size_t OFF_IDX   = OFF_CAND2 + CAND2_BYTES;
    const size_t OFF_ST    = OFF_IDX + IDX_BYTES;
    const size_t NEED_B    = OFF_ST + ST_BYTES;            // 38,056,256 (proven available)
    const size_t OFF_PSHI  = NEED_B;
    const size_t OFF_PSLO  = OFF_PSHI + PS_BYTES;
    const size_t OFF_PCHI  = OFF_PSLO + PS_BYTES;
    const size_t OFF_PCLO  = OFF_PCHI + PS_BYTES;
    const size_t NEED_A    = OFF_PCLO + PS_BYTES;          // 46,444,864

    unsigned short* Gb = (unsigned short*)d_ws;
    u64* cand2     = (u64*)((char*)d_ws + OFF_CAND2);
    int* idx       = (int*)((char*)d_ws + OFF_IDX);
    float* style_t = (float*)((char*)d_ws + OFF_ST);

    transpose_style<<<dim3(128, 8), 256, 0, stream>>>(style, style_t);

    if (ws_size >= NEED_A) {
        unsigned short* PShi = (unsigned short*)((char*)d_ws + OFF_PSHI);
        unsigned short* PSlo = (unsigned short*)((char*)d_ws + OFF_PSLO);
        unsigned short* PChi = (unsigned short*)((char*)d_ws + OFF_PCHI);
        unsigned short* PClo = (unsigned short*)((char*)d_ws + OFF_PCLO);

        split_panels<<<dim3(32, 8), 256, 0, stream>>>(style, PShi, PSlo);
        for (int b = 0; b < 4; ++b) {
            split_panels<<<dim3(32, 8), 256, 0, stream>>>(
                content + (size_t)b * NC * SP, PChi, PClo);
            g_gemm_p<<<dim3(32, 32), 256, 0, stream>>>(
                PChi, PClo, PShi, PSlo, Gb);
            stencil_direct<<<dim3(NP / 4), 256, 0, stream>>>(
                Gb, enc_bias, cand2, b);
        }
    } else {
        for (int b = 0; b < 4; ++b) {
            g_gemm<<<dim3(32, 32), 256, 0, stream>>>(
                content + (size_t)b * NC * SP, style, Gb);
            stencil_direct<<<dim3(NP / 4), 256, 0, stream>>>(
                Gb, enc_bias, cand2, b);
        }
    }

    rescore3<<<dim3(4 * NP), 128, 0, stream>>>(
        content, style_t, enc_bias, Gb, cand2, idx);
    produce_out2<<<dim3(4 * 64, 2), 256, 0, stream>>>(
        style_t, dec_bias, intra_bias, idx, out);
}

// Round 6
// 362.955 us; speedup vs baseline: 11.3266x; 1.1060x over previous
//
#include <hip/hip_runtime.h>
#include <stdint.h>

// Problem constants (B=4, C=256, H=W=64, PATCH=3, STRIDE=1)
#define NP   3844   // 62*62 patches == per-batch feat pixels
#define ND   62
#define NC   256
#define HW   64
#define SP   4096   // 64*64 pixels per image
#define SPSP ((size_t)SP * SP)      // G elements per batch
#define NCSP ((size_t)NC * SP)      // panel elements per batch
#define EPS_G 0.5f   // margin for gemm-internal (split/accum/sum) error
#define HULP 0.00390625f  // half-ulp factor for bf16 (2^-8)

typedef __attribute__((ext_vector_type(8))) short short8;
typedef __attribute__((ext_vector_type(8))) unsigned short ushort8;
typedef __attribute__((ext_vector_type(4))) float float4v;
typedef unsigned long long u64;

__device__ __forceinline__ unsigned int orderf(float v) {
    unsigned int u = __float_as_uint(v);
    return (u & 0x80000000u) ? ~u : (u | 0x80000000u);
}
__device__ __forceinline__ float unorderf(unsigned int k) {
    return __uint_as_float((k & 0x80000000u) ? (k ^ 0x80000000u) : ~k);
}
__device__ __forceinline__ float bf2f(unsigned short h) {
    return __uint_as_float(((unsigned int)h) << 16);
}
__device__ __forceinline__ unsigned short f2bf_rne(float a) {
    unsigned ua = __float_as_uint(a);
    return (unsigned short)((ua + 0x7fffu + ((ua >> 16) & 1u)) >> 16);
}

// ---------------------------------------------------------------------------
// Kernel 0: style_t[s][c] = style[c][s]  (4 MB fp32, for coalesced c-reads)
// ---------------------------------------------------------------------------
__global__ __launch_bounds__(256) void transpose_style(
    const float* __restrict__ style, float* __restrict__ style_t)
{
    __shared__ float t[32][33];
    const int s0 = blockIdx.x * 32;
    const int c0 = blockIdx.y * 32;
    const int col = threadIdx.x & 31, r8 = threadIdx.x >> 5;
    #pragma unroll
    for (int i = 0; i < 4; ++i) {
        int r = r8 + i * 8;
        t[r][col] = style[(size_t)(c0 + r) * SP + s0 + col];
    }
    __syncthreads();
    #pragma unroll
    for (int i = 0; i < 4; ++i) {
        int r = r8 + i * 8;
        style_t[(size_t)(s0 + r) * 256 + c0 + col] = t[col][r];
    }
}

// ---------------------------------------------------------------------------
// Kernel 0b: fp32 [256][4096] -> bf16 hi/lo in k-panel layout (batched over z)
// P[kp][s][j], kp=k/8, j=k%8: one MFMA fragment = ushort8 at ((kp*4096+s)*8).
// ---------------------------------------------------------------------------
__global__ __launch_bounds__(256) void split_panels(
    const float* __restrict__ src0,
    unsigned short* __restrict__ Phi0,
    unsigned short* __restrict__ Plo0)
{
    const float* src = src0 + (size_t)blockIdx.z * NCSP;
    unsigned short* Phi = Phi0 + (size_t)blockIdx.z * NCSP;
    unsigned short* Plo = Plo0 + (size_t)blockIdx.z * NCSP;

    __shared__ unsigned short hbuf[512 * 8];
    __shared__ unsigned short lbuf[512 * 8];
    const int kp = blockIdx.x;            // 0..31
    const int s0 = blockIdx.y * 512;      // 0..7
    const int tid = threadIdx.x;
    #pragma unroll
    for (int kk = 0; kk < 8; ++kk) {
        #pragma unroll
        for (int h = 0; h < 2; ++h) {
            int s = tid + h * 256;
            float a = src[(size_t)(kp * 8 + kk) * SP + s0 + s];
            unsigned short hi = f2bf_rne(a);
            float r = a - bf2f(hi);       // exact in fp32
            unsigned short lo = f2bf_rne(r);
            hbuf[s * 8 + kk] = hi;
            lbuf[s * 8 + kk] = lo;
        }
    }
    __syncthreads();
    #pragma unroll
    for (int h = 0; h < 2; ++h) {
        int s = tid + h * 256;
        size_t o = ((size_t)kp * 4096 + s0 + s) * 8;
        *(ushort8*)(Phi + o) = *(const ushort8*)(hbuf + s * 8);
        *(ushort8*)(Plo + o) = *(const ushort8*)(lbuf + s * 8);
    }
}

// ---------------------------------------------------------------------------
// Kernel 1: panel GEMM — G = content^T * style via bf16x3 MFMA, batched over z.
// Fragments loaded DIRECTLY from L2 (pre-split panels). No LDS, no barriers.
// ---------------------------------------------------------------------------
__global__ __launch_bounds__(256) void g_gemm_p(
    const unsigned short* __restrict__ Ahi0, const unsigned short* __restrict__ Alo0,
    const unsigned short* __restrict__ Bhi,  const unsigned short* __restrict__ Blo,
    unsigned short* __restrict__ G0)
{
    const unsigned short* Ahi = Ahi0 + (size_t)blockIdx.z * NCSP;
    const unsigned short* Alo = Alo0 + (size_t)blockIdx.z * NCSP;
    unsigned short* Gb = G0 + (size_t)blockIdx.z * SPSP;

    const int tid  = threadIdx.x;
    const int s0   = blockIdx.x * 128;
    const int t0   = blockIdx.y * 128;
    const int wave = tid >> 6, lane = tid & 63;
    const int wm = (wave >> 1) * 64, wn = (wave & 1) * 64;
    const int fr = lane & 15;
    const int fq = lane >> 4;     // k-quad -> panel offset

    float4v acc[4][4];
    #pragma unroll
    for (int i = 0; i < 4; ++i)
        #pragma unroll
        for (int j = 0; j < 4; ++j) acc[i][j] = (float4v)(0.f);

    size_t ra0[4], rb0[4];
    #pragma unroll
    for (int f = 0; f < 4; ++f) {
        ra0[f] = ((size_t)fq * 4096 + s0 + wm + f * 16 + fr) * 8;
        rb0[f] = ((size_t)fq * 4096 + t0 + wn + f * 16 + fr) * 8;
    }

    #pragma unroll 2
    for (int kq0 = 0; kq0 < 32; kq0 += 4) {
        const size_t pan = (size_t)kq0 * 4096 * 8;
        short8 ah[4], al[4], bh[4], bl[4];
        #pragma unroll
        for (int f = 0; f < 4; ++f) {
            ah[f] = *(const short8*)(Ahi + pan + ra0[f]);
            al[f] = *(const short8*)(Alo + pan + ra0[f]);
            bh[f] = *(const short8*)(Bhi + pan + rb0[f]);
            bl[f] = *(const short8*)(Blo + pan + rb0[f]);
        }
        #pragma unroll
        for (int fm = 0; fm < 4; ++fm)
            #pragma unroll
            for (int fn = 0; fn < 4; ++fn) {
                acc[fm][fn] = __builtin_amdgcn_mfma_f32_16x16x32_bf16(ah[fm], bh[fn], acc[fm][fn], 0, 0, 0);
                acc[fm][fn] = __builtin_amdgcn_mfma_f32_16x16x32_bf16(ah[fm], bl[fn], acc[fm][fn], 0, 0, 0);
                acc[fm][fn] = __builtin_amdgcn_mfma_f32_16x16x32_bf16(al[fm], bh[fn], acc[fm][fn], 0, 0, 0);
            }
    }

    // store: C/D layout col=lane&15, row=(lane>>4)*4+reg  (validated)
    #pragma unroll
    for (int fm = 0; fm < 4; ++fm)
        #pragma unroll
        for (int fn = 0; fn < 4; ++fn)
            #pragma unroll
            for (int r = 0; r < 4; ++r) {
                unsigned short o = f2bf_rne(acc[fm][fn][r]);
                Gb[(size_t)(s0 + wm + fm * 16 + fq * 4 + r) * SP + t0 + wn + fn * 16 + fr] = o;
            }
}

// ---------------------------------------------------------------------------
// Kernel 1-fallback (round-3/4 validated): LDS-staged split GEMM (fp32 input)
// ---------------------------------------------------------------------------
__global__ __launch_bounds__(256, 2) void g_gemm(
    const float* __restrict__ contentb,
    const float* __restrict__ style,
    unsigned short* __restrict__ Gb)
{
    __shared__ __attribute__((aligned(16))) short Ah[4 * 128 * 8];
    __shared__ __attribute__((aligned(16))) short Al[4 * 128 * 8];
    __shared__ __attribute__((aligned(16))) short Bh[4 * 128 * 8];
    __shared__ __attribute__((aligned(16))) short Bl[4 * 128 * 8];

    const int tid  = threadIdx.x;
    const int s0   = blockIdx.x * 128;
    const int t0   = blockIdx.y * 128;
    const int wave = tid >> 6, lane = tid & 63;
    const int wm = (wave >> 1) * 64, wn = (wave & 1) * 64;
    const int fr = lane & 15;
    const int fq = lane >> 4;
    const int sm = tid & 127;
    const int sl = tid >> 7;

    float4v acc[4][4];
    #pragma unroll
    for (int i = 0; i < 4; ++i)
        #pragma unroll
        for (int j = 0; j < 4; ++j) acc[i][j] = (float4v)(0.f);

    for (int k0 = 0; k0 < 256; k0 += 32) {
        __syncthreads();
        #pragma unroll
        for (int h = 0; h < 2; ++h) {
            const float* src = h ? style : contentb;
            const int rb = h ? t0 : s0;
            short* dh = h ? Bh : Ah;
            short* dl = h ? Bl : Al;
            float v[16];
            #pragma unroll
            for (int j = 0; j < 16; ++j)
                v[j] = src[(size_t)(k0 + sl * 16 + j) * SP + rb + sm];
            short8 h0, h1, l0, l1;
            #pragma unroll
            for (int j = 0; j < 8; ++j) {
                unsigned ua = __float_as_uint(v[j]);
                unsigned ub = __float_as_uint(v[j + 8]);
                h0[j] = (short)(ua >> 16);
                h1[j] = (short)(ub >> 16);
                float ra  = v[j]     - __uint_as_float(ua & 0xffff0000u);
                float rb2 = v[j + 8] - __uint_as_float(ub & 0xffff0000u);
                l0[j] = (short)(__float_as_uint(ra) >> 16);
                l1[j] = (short)(__float_as_uint(rb2) >> 16);
            }
            *(short8*)(dh + ((sl * 2)     * 128 + sm) * 8) = h0;
            *(short8*)(dh + ((sl * 2 + 1) * 128 + sm) * 8) = h1;
            *(short8*)(dl + ((sl * 2)     * 128 + sm) * 8) = l0;
            *(short8*)(dl + ((sl * 2 + 1) * 128 + sm) * 8) = l1;
        }
        __syncthreads();

        short8 ah[4], al[4], bh[4], bl[4];
        #pragma unroll
        for (int f = 0; f < 4; ++f) {
            const int ra = (fq * 128 + wm + f * 16 + fr) * 8;
            const int rb = (fq * 128 + wn + f * 16 + fr) * 8;
            ah[f] = *(const short8*)(Ah + ra);
            al[f] = *(const short8*)(Al + ra);
            bh[f] = *(const short8*)(Bh + rb);
            bl[f] = *(const short8*)(Bl + rb);
        }
        #pragma unroll
        for (int fm = 0; fm < 4; ++fm)
            #pragma unroll
            for (int fn = 0; fn < 4; ++fn) {
                acc[fm][fn] = __builtin_amdgcn_mfma_f32_16x16x32_bf16(ah[fm], bh[fn], acc[fm][fn], 0, 0, 0);
                acc[fm][fn] = __builtin_amdgcn_mfma_f32_16x16x32_bf16(ah[fm], bl[fn], acc[fm][fn], 0, 0, 0);
                acc[fm][fn] = __builtin_amdgcn_mfma_f32_16x16x32_bf16(al[fm], bh[fn], acc[fm][fn], 0, 0, 0);
            }
    }

    #pragma unroll
    for (int fm = 0; fm < 4; ++fm)
        #pragma unroll
        for (int fn = 0; fn < 4; ++fn)
            #pragma unroll
            for (int r = 0; r < 4; ++r) {
                unsigned short o = f2bf_rne(acc[fm][fn][r]);
                Gb[(size_t)(s0 + wm + fm * 16 + fq * 4 + r) * SP + t0 + wn + fn * 16 + fr] = o;
            }
}

// ---------------------------------------------------------------------------
// Kernel 2: direct-G vectorized stencil + global per-q top-2 (validated),
// batched: blockIdx.y = local batch; cand batch = bbase + local.
// ---------------------------------------------------------------------------
__global__ __launch_bounds__(256) void stencil_direct(
    const unsigned short* __restrict__ G0,
    const float* __restrict__ enc_bias,
    u64* __restrict__ cand2, int bbase)
{
    const int bl = blockIdx.y;
    const unsigned short* G = G0 + (size_t)bl * SPSP;
    const int b = bbase + bl;

    const int q = blockIdx.x * 4 + (threadIdx.x >> 6);
    const int lane = threadIdx.x & 63;
    const int y = q / ND, x = q - y * ND;
    const int jg = (lane & 7) * 8;
    const int ig = lane >> 3;
    const unsigned short* Gq = G + (size_t)(y * 64 + x) * SP;

    u64 k1 = 0, k2 = 0;
    for (int it = 0; it < 8; ++it) {
        const int i = it * 8 + ig;
        if (i <= 61) {
            float f[8];
            #pragma unroll
            for (int j = 0; j < 8; ++j) f[j] = 0.f;
            #pragma unroll
            for (int u = 0; u < 3; ++u) {
                #pragma unroll
                for (int v = 0; v < 3; ++v) {
                    const unsigned short* rp =
                        Gq + (size_t)(u * 64 + v) * SP + (i + u) * 64 + jg;
                    ushort8 a = *(const ushort8*)rp;
                    unsigned e = (jg < 56) ? *(const unsigned*)(rp + 8) : 0u;
                    float w8 = bf2f((unsigned short)(e & 0xffffu));
                    float w9 = bf2f((unsigned short)(e >> 16));
                    if (v == 0) {
                        #pragma unroll
                        for (int j = 0; j < 8; ++j) f[j] += bf2f(a[j]);
                    } else if (v == 1) {
                        #pragma unroll
                        for (int j = 0; j < 7; ++j) f[j] += bf2f(a[j + 1]);
                        f[7] += w8;
                    } else {
                        #pragma unroll
                        for (int j = 0; j < 6; ++j) f[j] += bf2f(a[j + 2]);
                        f[6] += w8;
                        f[7] += w9;
                    }
                }
            }
            #pragma unroll
            for (int j = 0; j < 8; ++j) {
                int jj = jg + j;
                if (jj <= 61) {
                    int p = i * ND + jj;
                    float fv = f[j] + enc_bias[p];
                    u64 key = ((u64)orderf(fv) << 32) | (unsigned)(NP - 1 - p);
                    if (key > k1) { k2 = k1; k1 = key; }
                    else if (key > k2) k2 = key;
                }
            }
        }
    }

    #pragma unroll
    for (int d = 1; d < 64; d <<= 1) {
        u64 o1 = __shfl_xor(k1, d, 64);
        u64 o2 = __shfl_xor(k2, d, 64);
        u64 hi = k1 > o1 ? k1 : o1;
        u64 lo = k1 > o1 ? o1 : k1;
        u64 m2 = k2 > o2 ? k2 : o2;
        k1 = hi;
        k2 = lo > m2 ? lo : m2;
    }
    if (lane == 0) {
        size_t o = (size_t)(b * NP + q) * 2;
        cand2[o] = k1;
        cand2[o + 1] = k2;
    }
}

// ---------------------------------------------------------------------------
// Kernel 3: half-ulp-sum error bound + gap-skip + exact fp32 rescore.
// Batched: blockIdx.x covers nb*NP q's; G base resolved per local batch.
// ---------------------------------------------------------------------------
__global__ __launch_bounds__(128) void rescore4(
    const float* __restrict__ content,
    const float* __restrict__ style_t,   // [s][c]
    const float* __restrict__ enc_bias,
    const unsigned short* __restrict__ G0,
    const u64* __restrict__ cand2,
    int* __restrict__ idx, int bbase)
{
    __shared__ float sc[2];
    __shared__ int   pp[2];
    const int bl = blockIdx.x / NP;
    const int q  = blockIdx.x - bl * NP;
    const int b  = bbase + bl;
    const int qa = b * NP + q;
    const unsigned short* G = G0 + (size_t)bl * SPSP;
    const int tid = threadIdx.x;
    const int wave = tid >> 6, lane = tid & 63;
    const int y = q / ND, x = q - y * ND;

    const u64 k1 = cand2[(size_t)qa * 2];
    const u64 k2 = cand2[(size_t)qa * 2 + 1];
    const int p1 = NP - 1 - (int)(k1 & 0xffffffffu);
    const int p2 = NP - 1 - (int)(k2 & 0xffffffffu);
    const float f1 = unorderf((unsigned int)(k1 >> 32));
    const float f2 = unorderf((unsigned int)(k2 >> 32));

    if (k2 == 0ull) {
        if (tid == 0) idx[qa] = p1;
        return;
    }

    // data-dependent screening bound: E = sum_9 halfulp(G_d) per candidate
    float eul = 0.f;
    {
        const int side = lane >> 4;            // lanes 0-8 -> p1, 16-24 -> p2
        const int d = lane & 15;
        if (side < 2 && d < 9) {
            int u = d / 3, v = d - u * 3;
            int pc = side ? p2 : p1;
            int pi = pc / ND, pj = pc - pi * ND;
            unsigned short g = G[(size_t)((y + u) * 64 + x + v) * SP
                                 + (pi + u) * 64 + pj + v];
            float gf = bf2f(g);
            eul = __uint_as_float(__float_as_uint(gf) & 0x7f800000u) * HULP;
        }
    }
    #pragma unroll
    for (int d = 1; d < 64; d <<= 1) eul += __shfl_xor(eul, d, 64);
    // eul now = E(p1) + E(p2) on every lane

    if ((f1 - f2) > eul + EPS_G) {
        if (tid == 0) idx[qa] = p1;
        return;
    }

    const int pc = wave ? p2 : p1;
    const int pi = pc / ND, pj = pc - pi * ND;
    const int off_c = y * 64 + x;
    const int off_s = pi * 64 + pj;
    float s = 0.f;
    #pragma unroll
    for (int g = 0; g < 4; ++g) {
        const int c = g * 64 + lane;
        const float* cw = content + ((size_t)b * NC + c) * SP + off_c;
        const float* sw = style_t + (size_t)off_s * 256 + c;
        #pragma unroll
        for (int u = 0; u < 3; ++u)
            #pragma unroll
            for (int v = 0; v < 3; ++v)
                s = fmaf(cw[u * 64 + v], sw[(size_t)(u * 64 + v) * 256], s);
    }
    #pragma unroll
    for (int d = 32; d; d >>= 1) s += __shfl_xor(s, d, 64);
    if (lane == 0) { sc[wave] = s + enc_bias[pc]; pp[wave] = pc; }
    __syncthreads();
    if (tid == 0) {
        float s0 = sc[0], s1 = sc[1];
        int q0 = pp[0], q1 = pp[1];
        idx[qa] = (s1 > s0 || (s1 == s0 && q1 < q0)) ? q1 : q0;
    }
}

// ---------------------------------------------------------------------------
// Kernel 4: output via style_t with LDS row accumulation (validated)
// ---------------------------------------------------------------------------
__global__ __launch_bounds__(256) void produce_out2(
    const float* __restrict__ style_t,
    const float* __restrict__ dec_bias,
    const float* __restrict__ intra_bias,
    const int* __restrict__ idx,
    float* __restrict__ out)
{
    __shared__ float orow[64][129];
    __shared__ int pidx[3][ND];

    const int bh = blockIdx.x;
    const int b = bh >> 6, h = bh & 63;
    const int ch = blockIdx.y;
    const int tid = threadIdx.x;

    if (tid < 3 * ND) {
        int u = tid / ND, xx = tid - u * ND;
        int yy = h - u;
        pidx[u][xx] = (yy >= 0 && yy < ND) ? idx[b * NP + yy * ND + xx] : 0;
    }
    for (int i = tid; i < 64 * 129; i += 256) ((float*)orow)[i] = 0.f;
    __syncthreads();

    const int cl = tid & 127;
    const int xo = tid >> 7;
    for (int u = 0; u < 3; ++u) {
        int yy = h - u;
        if (yy < 0 || yy >= ND) continue;
        #pragma unroll
        for (int v = 0; v < 3; ++v) {
            for (int xi = (xo + v) & 1; xi < ND; xi += 2) {
                int p = pidx[u][xi];
                int pi = p / ND, pj = p - pi * ND;
                float sv = style_t[(size_t)(pi * 64 + pj + u * 64 + v) * 256 + ch * 128 + cl];
                orow[xi + v][cl] += sv;
            }
        }
    }
    __syncthreads();

    const int w = tid & 63, cg = tid >> 6;
    const int cu  = (h < 2 ? h : 2) - (h > 61 ? h - 61 : 0) + 1;
    const int cvw = (w < 2 ? w : 2) - (w > 61 ? w - 61 : 0) + 1;
    const float cnt = (float)(cu * cvw);
    #pragma unroll 4
    for (int ci = 0; ci < 32; ++ci) {
        int cll = cg * 32 + ci;
        int c = ch * 128 + cll;
        float val = (orow[w][cll] + dec_bias[c]) / (cnt + intra_bias[c]);
        out[(((size_t)b * NC + c) * 64 + h) * 64 + w] = val;
    }
}

// ---------------------------------------------------------------------------
extern "C" void kernel_launch(void* const* d_in, const int* in_sizes, int n_in,
                              void* d_out, int out_size, void* d_ws, size_t ws_size,
                              hipStream_t stream) {
    const float* content    = (const float*)d_in[0];
    const float* style      = (const float*)d_in[1];
    const float* enc_bias   = (const float*)d_in[2];
    const float* dec_bias   = (const float*)d_in[3];
    const float* intra_bias = (const float*)d_in[4];
    float* out = (float*)d_out;

    const size_t G_BYTES     = SPSP * 2;                   //  33,554,432
    const size_t CAND2_BYTES = (size_t)4 * NP * 2 * 8;     //     246,016
    const size_t IDX_BYTES   = (size_t)4 * NP * 4;         //      61,504
    const size_t ST_BYTES    = NCSP * 16;                  //   4,194,304 (fp32 4096x256)
    const size_t PS_BYTES    = NCSP * 2;                   //   2,097,152

    // Tier B (round-5-proven, 38 MB): single G + per-batch loop
    const size_t OFF_CAND2 = 4 * G_BYTES;                  // tier-A: after G4
    const size_t OFF_CAND2_B = G_BYTES;                    // tier-B
    // Tier A layout
    const size_t A_OFF_IDX  = OFF_CAND2 + CAND2_BYTES;
    const size_t A_OFF_ST   = A_OFF_IDX + IDX_BYTES;
    const size_t A_OFF_PSHI = A_OFF_ST + ST_BYTES;
    const size_t A_OFF_PSLO = A_OFF_PSHI + PS_BYTES;
    const size_t A_OFF_PCHI = A_OFF_PSLO + PS_BYTES;
    const size_t A_OFF_PCLO = A_OFF_PCHI + 4 * PS_BYTES;
    const size_t NEED_A     = A_OFF_PCLO + 4 * PS_BYTES;   // ~159.8 MB
    // Tier B layout
    const size_t B_OFF_IDX = OFF_CAND2_B + CAND2_BYTES;
    const size_t B_OFF_ST  = B_OFF_IDX + IDX_BYTES;
    const size_t NEED_B    = B_OFF_ST + ST_BYTES;          // 38,056,256

    if (ws_size >= NEED_A) {
        unsigned short* G4   = (unsigned short*)d_ws;
        u64* cand2           = (u64*)((char*)d_ws + OFF_CAND2);
        int* idx             = (int*)((char*)d_ws + A_OFF_IDX);
        float* style_t       = (float*)((char*)d_ws + A_OFF_ST);
        unsigned short* PShi = (unsigned short*)((char*)d_ws + A_OFF_PSHI);
        unsigned short* PSlo = (unsigned short*)((char*)d_ws + A_OFF_PSLO);
        unsigned short* PChi = (unsigned short*)((char*)d_ws + A_OFF_PCHI);
        unsigned short* PClo = (unsigned short*)((char*)d_ws + A_OFF_PCLO);

        transpose_style<<<dim3(128, 8), 256, 0, stream>>>(style, style_t);
        split_panels<<<dim3(32, 8, 1), 256, 0, stream>>>(style, PShi, PSlo);
        split_panels<<<dim3(32, 8, 4), 256, 0, stream>>>(content, PChi, PClo);
        g_gemm_p<<<dim3(32, 32, 4), 256, 0, stream>>>(PChi, PClo, PShi, PSlo, G4);
        stencil_direct<<<dim3(NP / 4, 4), 256, 0, stream>>>(G4, enc_bias, cand2, 0);
        rescore4<<<dim3(4 * NP), 128, 0, stream>>>(
            content, style_t, enc_bias, G4, cand2, idx, 0);
        produce_out2<<<dim3(4 * 64, 2), 256, 0, stream>>>(
            style_t, dec_bias, intra_bias, idx, out);
    } else {
        unsigned short* Gb = (unsigned short*)d_ws;
        u64* cand2     = (u64*)((char*)d_ws + OFF_CAND2_B);
        int* idx       = (int*)((char*)d_ws + B_OFF_IDX);
        float* style_t = (float*)((char*)d_ws + B_OFF_ST);

        transpose_style<<<dim3(128, 8), 256, 0, stream>>>(style, style_t);
        for (int b = 0; b < 4; ++b) {
            g_gemm<<<dim3(32, 32), 256, 0, stream>>>(
                content + (size_t)b * NCSP, style, Gb);
            stencil_direct<<<dim3(NP / 4, 1), 256, 0, stream>>>(
                Gb, enc_bias, cand2, b);
            rescore4<<<dim3(NP), 128, 0, stream>>>(
                content, style_t, enc_bias, Gb, cand2, idx, b);
        }
        produce_out2<<<dim3(4 * 64, 2), 256, 0, stream>>>(
            style_t, dec_bias, intra_bias, idx, out);
    }
}